// Round 1
// baseline (975.993 us; speedup 1.0000x reference)
//
#include <hip/hip_runtime.h>
#include <stdint.h>
#include <math.h>

typedef __attribute__((ext_vector_type(8))) short short8;
typedef __attribute__((ext_vector_type(4))) float f32x4;

__device__ __forceinline__ float b2f(unsigned short u) {
    union { unsigned int i; float f; } v; v.i = ((unsigned int)u) << 16; return v.f;
}
__device__ __forceinline__ unsigned short f2b(float f) {
    union { float f; unsigned int i; } v; v.f = f;
    unsigned int r = v.i + 0x7fffu + ((v.i >> 16) & 1u);
    return (unsigned short)(r >> 16);
}

__device__ __forceinline__ void gload_lds16(const void* g, void* l) {
    __builtin_amdgcn_global_load_lds((__attribute__((address_space(1))) void*)g,
                                     (__attribute__((address_space(3))) void*)l,
                                     16, 0, 0);
}

// ---------------------------------------------------------------------------
// Generic bf16 MFMA GEMM: C[row][col] = sum_k A[row*lda + k] * Bw[col*K + k]
// A: (rows, K) with row-stride lda (lda may be < K: overlapping conv rows)
// Bw: (Ncols, K)  (i.e. W^T, K-contiguous)
// 128x128 tile, BK=32, 4 waves, 4x4 16x16x32 frags per wave.
// EPI: 0 = bias + bf16 store; 1 = bias + silu + bf16 store;
//      2 = bias + f32 store;  3 = bias + sigmoid * Yin added into Cf (f32)
// ---------------------------------------------------------------------------
template<int EPI>
__global__ __launch_bounds__(256)
void gemm_bt(const unsigned short* __restrict__ A, long sAb, int lda,
             const unsigned short* __restrict__ Bw,
             const float* __restrict__ bias, int K,
             unsigned short* __restrict__ Cb, long sCb, int ldc,
             float* __restrict__ Cf, const float* __restrict__ Yin)
{
    __shared__ __align__(16) unsigned short As[128 * 32];
    __shared__ __align__(16) unsigned short Bs[128 * 32];
    const int tid = threadIdx.x;
    const int lane = tid & 63, wid = tid >> 6;
    const int wr = wid >> 1, wc = wid & 1;
    const int z = blockIdx.z;
    const long brow = (long)blockIdx.y * 128;
    const long bcol = (long)blockIdx.x * 128;
    const unsigned short* Ab = A + (long)z * sAb;

    const int arow = tid >> 2;          // 0..63
    const int acol = (tid & 3) * 8;
    const unsigned short* ga0 = Ab + (brow + arow) * (long)lda + acol;
    const unsigned short* ga1 = Ab + (brow + 64 + arow) * (long)lda + acol;
    const unsigned short* gb0 = Bw + (bcol + arow) * (long)K + acol;
    const unsigned short* gb1 = Bw + (bcol + 64 + arow) * (long)K + acol;
    unsigned short* la0 = As + wid * 512;
    unsigned short* la1 = As + 2048 + wid * 512;
    unsigned short* lb0 = Bs + wid * 512;
    unsigned short* lb1 = Bs + 2048 + wid * 512;

    f32x4 acc[4][4] = {};

    for (int kk = 0; kk < K; kk += 32) {
        gload_lds16(ga0 + kk, la0);
        gload_lds16(ga1 + kk, la1);
        gload_lds16(gb0 + kk, lb0);
        gload_lds16(gb1 + kk, lb1);
        __syncthreads();
        const int fr = lane & 15, fk = (lane >> 4) * 8;
        short8 af[4], bfrag[4];
#pragma unroll
        for (int m = 0; m < 4; m++)
            af[m] = *(const short8*)(As + (wr * 64 + m * 16 + fr) * 32 + fk);
#pragma unroll
        for (int n = 0; n < 4; n++)
            bfrag[n] = *(const short8*)(Bs + (wc * 64 + n * 16 + fr) * 32 + fk);
#pragma unroll
        for (int m = 0; m < 4; m++)
#pragma unroll
            for (int n = 0; n < 4; n++)
                acc[m][n] = __builtin_amdgcn_mfma_f32_16x16x32_bf16(af[m], bfrag[n], acc[m][n], 0, 0, 0);
        __syncthreads();
    }

    const int fr = lane & 15;
    const int fq = (lane >> 4) * 4;
#pragma unroll
    for (int m = 0; m < 4; m++) {
#pragma unroll
        for (int n = 0; n < 4; n++) {
#pragma unroll
            for (int j = 0; j < 4; j++) {
                long row = brow + wr * 64 + m * 16 + fq + j;
                long col = bcol + wc * 64 + n * 16 + fr;
                float v = acc[m][n][j] + bias[col];
                if (EPI == 0) {
                    Cb[z * sCb + row * ldc + col] = f2b(v);
                } else if (EPI == 1) {
                    float sg = 1.f / (1.f + expf(-v));
                    Cb[z * sCb + row * ldc + col] = f2b(v * sg);
                } else if (EPI == 2) {
                    Cf[row * ldc + col] = v;
                } else {
                    float sg = 1.f / (1.f + expf(-v));
                    long idx = row * 1024 + col;
                    Cf[idx] += sg * Yin[idx];
                }
            }
        }
    }
}

// ---------------------------------------------------------------------------
// Flash attention: qkv (B,N,3,H,dh) bf16 (roped), bias plog[b][key], out y (B,N,H*dh) bf16
// grid (16 qtiles, 64 bh), 256 threads. Wave w: q rows qt*64+w*16..+16.
// ---------------------------------------------------------------------------
__global__ __launch_bounds__(256)
void attn_kernel(const unsigned short* __restrict__ qkv,
                 const float* __restrict__ plog,
                 unsigned short* __restrict__ y)
{
    __shared__ __align__(16) unsigned short Ks[32 * 64];
    __shared__ __align__(16) unsigned short Vt[64 * 32];
    __shared__ __align__(16) unsigned short Ps[4 * 16 * 32];
    __shared__ float pl[1024];

    const int qt = blockIdx.x;
    const int bh = blockIdx.y;
    const int b = bh >> 4, h = bh & 15;
    const int tid = threadIdx.x, lane = tid & 63, wid = tid >> 6;

    const long nb = (long)b * 1024;
    const unsigned short* qbase = qkv + nb * 3072 + h * 64;
    const unsigned short* kbase = qbase + 1024;
    const unsigned short* vbase = qbase + 2048;

    for (int i = tid; i < 1024; i += 256) pl[i] = plog[b * 1024 + i];

    const int fr = lane & 15, g = lane >> 4;
    const int q0 = qt * 64 + wid * 16;
    const long qrow = q0 + fr;
    short8 aq0 = *(const short8*)(qbase + qrow * 3072 + g * 8);
    short8 aq1 = *(const short8*)(qbase + qrow * 3072 + 32 + g * 8);

    float m_st[4] = {-1e30f, -1e30f, -1e30f, -1e30f};
    float l_st[4] = {0.f, 0.f, 0.f, 0.f};
    f32x4 o[4] = {};

    unsigned short* Psw = Ps + wid * 512;

    const int skey = tid >> 3, spart = tid & 7;
    const unsigned short* gk = kbase + (long)skey * 3072 + spart * 8;
    const unsigned short* gv = vbase + (long)skey * 3072 + spart * 8;
    unsigned short* lk = Ks + wid * 512;

    for (int kt = 0; kt < 1024; kt += 32) {
        __syncthreads();
        gload_lds16(gk + (long)kt * 3072, lk);
        short8 vv = *(const short8*)(gv + (long)kt * 3072);
#pragma unroll
        for (int j = 0; j < 8; j++)
            Vt[(spart * 8 + j) * 32 + skey] = (unsigned short)vv[j];
        __syncthreads();

        f32x4 sc[2];
#pragma unroll
        for (int n = 0; n < 2; n++) {
            short8 bk0 = *(const short8*)(Ks + (n * 16 + fr) * 64 + g * 8);
            short8 bk1 = *(const short8*)(Ks + (n * 16 + fr) * 64 + 32 + g * 8);
            f32x4 t = {};
            t = __builtin_amdgcn_mfma_f32_16x16x32_bf16(aq0, bk0, t, 0, 0, 0);
            t = __builtin_amdgcn_mfma_f32_16x16x32_bf16(aq1, bk1, t, 0, 0, 0);
            sc[n] = t;
        }

        float pl0 = pl[kt + fr], pl1 = pl[kt + 16 + fr];
#pragma unroll
        for (int j = 0; j < 4; j++) {
            float s0 = sc[0][j] * 0.125f + pl0;
            float s1 = sc[1][j] * 0.125f + pl1;
            float mx = fmaxf(s0, s1);
            mx = fmaxf(mx, __shfl_xor(mx, 1));
            mx = fmaxf(mx, __shfl_xor(mx, 2));
            mx = fmaxf(mx, __shfl_xor(mx, 4));
            mx = fmaxf(mx, __shfl_xor(mx, 8));
            float mnew = fmaxf(m_st[j], mx);
            float f = expf(m_st[j] - mnew);
            float p0 = expf(s0 - mnew);
            float p1 = expf(s1 - mnew);
            float rs = p0 + p1;
            rs += __shfl_xor(rs, 1);
            rs += __shfl_xor(rs, 2);
            rs += __shfl_xor(rs, 4);
            rs += __shfl_xor(rs, 8);
            l_st[j] = l_st[j] * f + rs;
            m_st[j] = mnew;
#pragma unroll
            for (int n2 = 0; n2 < 4; n2++) o[n2][j] *= f;
            Psw[(g * 4 + j) * 32 + fr] = f2b(p0);
            Psw[(g * 4 + j) * 32 + 16 + fr] = f2b(p1);
        }

        short8 ap = *(const short8*)(Psw + fr * 32 + g * 8);
#pragma unroll
        for (int n2 = 0; n2 < 4; n2++) {
            short8 bv = *(const short8*)(Vt + (n2 * 16 + fr) * 32 + g * 8);
            o[n2] = __builtin_amdgcn_mfma_f32_16x16x32_bf16(ap, bv, o[n2], 0, 0, 0);
        }
    }

#pragma unroll
    for (int j = 0; j < 4; j++) {
        float inv = 1.f / l_st[j];
        long row = nb + q0 + g * 4 + j;
#pragma unroll
        for (int n2 = 0; n2 < 4; n2++)
            y[row * 1024 + h * 64 + n2 * 16 + fr] = f2b(o[n2][j] * inv);
    }
}

// --------------------------------------------------------------------------
__global__ __launch_bounds__(256)
void zcrms_kernel(const float* __restrict__ x, const float* __restrict__ g,
                  unsigned short* __restrict__ hn)
{
    __shared__ float red[8];
    const long row = blockIdx.x;
    const int tid = threadIdx.x;
    const float* xr = x + row * 1024;
    float4 v = *(const float4*)(xr + tid * 4);
    float s = v.x + v.y + v.z + v.w;
#pragma unroll
    for (int m = 32; m; m >>= 1) s += __shfl_xor(s, m);
    const int lane = tid & 63, wid = tid >> 6;
    if (lane == 0) red[wid] = s;
    __syncthreads();
    float mean = (red[0] + red[1] + red[2] + red[3]) * (1.f / 1024.f);
    float c0 = v.x - mean, c1 = v.y - mean, c2 = v.z - mean, c3 = v.w - mean;
    float s2 = c0 * c0 + c1 * c1 + c2 * c2 + c3 * c3;
#pragma unroll
    for (int m = 32; m; m >>= 1) s2 += __shfl_xor(s2, m);
    if (lane == 0) red[4 + wid] = s2;
    __syncthreads();
    float rinv = rsqrtf((red[4] + red[5] + red[6] + red[7]) * (1.f / 1024.f) + 1e-8f);
    const float* gr = g + tid * 4;
    unsigned int lo = (unsigned int)f2b(c0 * rinv * gr[0]) | ((unsigned int)f2b(c1 * rinv * gr[1]) << 16);
    unsigned int hi = (unsigned int)f2b(c2 * rinv * gr[2]) | ((unsigned int)f2b(c3 * rinv * gr[3]) << 16);
    uint2 u; u.x = lo; u.y = hi;
    *(uint2*)(hn + row * 1024 + tid * 4) = u;
}

__global__ __launch_bounds__(1024)
void embed_kernel(const float* __restrict__ patches, const float* __restrict__ W,
                  const float* __restrict__ bias, float* __restrict__ x,
                  unsigned short* __restrict__ xpad)
{
    __shared__ float sp[8][75];
    const long r0 = (long)blockIdx.x * 8;
    const int tid = threadIdx.x;
    for (int i = tid; i < 600; i += 1024) sp[i / 75][i % 75] = patches[r0 * 75 + i];
    __syncthreads();
    float acc[8];
    float bb = bias[tid];
#pragma unroll
    for (int j = 0; j < 8; j++) acc[j] = bb;
    for (int p = 0; p < 75; p++) {
        float w = W[p * 1024 + tid];
#pragma unroll
        for (int j = 0; j < 8; j++) acc[j] += sp[j][p] * w;
    }
#pragma unroll
    for (int j = 0; j < 8; j++) {
        long r = r0 + j;
        x[r * 1024 + tid] = acc[j];
        long bb2 = r >> 10, n = r & 1023;
        xpad[(bb2 * 1028 + n + 2) * 1024 + tid] = f2b(acc[j]);
    }
}

__global__ void rope_table_kernel(float* __restrict__ tab)
{
    int idx = blockIdx.x * 256 + threadIdx.x;   // 32768
    int n = idx >> 5, i = idx & 31;
    float inv = powf(10000.0f, -(float)i * (1.0f / 32.0f));
    float ang = (float)n * inv;
    tab[idx] = cosf(ang);
    tab[32768 + idx] = sinf(ang);
}

__global__ void rope_kernel(unsigned short* __restrict__ qkv, const float* __restrict__ tab)
{
    long idx = (long)blockIdx.x * 256 + threadIdx.x;   // 4194304
    int i = (int)(idx & 31);
    int h = (int)((idx >> 5) & 15);
    int w2 = (int)((idx >> 9) & 1);
    int n = (int)((idx >> 10) & 1023);
    int b = (int)(idx >> 20);
    long base = ((long)((b * 1024 + n) * 3 + w2)) * 1024 + h * 64 + 2 * i;
    float x0 = b2f(qkv[base]);
    float x1 = b2f(qkv[base + 1]);
    float c = tab[n * 32 + i], sn = tab[32768 + n * 32 + i];
    qkv[base] = f2b(x0 * c - x1 * sn);
    qkv[base + 1] = f2b(x0 * sn + x1 * c);
}

__global__ __launch_bounds__(256)
void conv3_kernel(const unsigned short* __restrict__ h2, const float* __restrict__ w3,
                  const float* __restrict__ b3, float* __restrict__ logits)
{
    const long row = (long)blockIdx.x * 4 + (threadIdx.x >> 6);
    const int lane = threadIdx.x & 63;
    const unsigned short* hr = h2 + row * 256;
    float s = 0.f;
#pragma unroll
    for (int t = 0; t < 4; t++) s += b2f(hr[lane + t * 64]) * w3[lane + t * 64];
#pragma unroll
    for (int m = 32; m; m >>= 1) s += __shfl_xor(s, m);
    if (lane == 0) logits[row] = s + b3[0];
}

__global__ __launch_bounds__(256)
void winmax_kernel(const float* __restrict__ logits, float* __restrict__ win)
{
    __shared__ float red[4];
    const int b = blockIdx.x, tid = threadIdx.x;
    float m = -1e30f;
    for (int i = tid; i < 1024; i += 256) m = fmaxf(m, logits[b * 1024 + i]);
#pragma unroll
    for (int k = 32; k; k >>= 1) m = fmaxf(m, __shfl_xor(m, k));
    if ((tid & 63) == 0) red[tid >> 6] = m;
    __syncthreads();
    if (tid == 0) win[b] = fmaxf(fmaxf(red[0], red[1]), fmaxf(red[2], red[3]));
}

// f32 (K,Nc) -> bf16 (Nc,K), batched over z
__global__ __launch_bounds__(256)
void wtrans_kernel(const float* __restrict__ in, unsigned short* __restrict__ out,
                   int K, int Nc)
{
    __shared__ float tile[32][33];
    const long base = (long)blockIdx.z * K * Nc;
    const int k0 = blockIdx.y * 32, n0 = blockIdx.x * 32;
    const int tx = threadIdx.x & 31, ty = threadIdx.x >> 5;
#pragma unroll
    for (int r = ty; r < 32; r += 8) tile[r][tx] = in[base + (long)(k0 + r) * Nc + n0 + tx];
    __syncthreads();
#pragma unroll
    for (int r = ty; r < 32; r += 8) out[base + (long)(n0 + r) * K + k0 + tx] = f2b(tile[tx][r]);
}

// (Co,Ci,Kw) f32 -> (Co, Kw*Ci) bf16 with k = dk*Ci + ci
__global__ void wconv_trans_kernel(const float* __restrict__ in, unsigned short* __restrict__ out,
                                   int Ci, int Kw, long total)
{
    long idx = (long)blockIdx.x * 256 + threadIdx.x;
    if (idx >= total) return;
    long ck = (long)Ci * Kw;
    int co = (int)(idx / ck);
    int rem = (int)(idx % ck);
    int dk = rem / Ci, ci = rem % Ci;
    out[idx] = f2b(in[(long)co * ck + (long)ci * Kw + dk]);
}

__global__ void finalize_kernel(const float* __restrict__ x, const float* __restrict__ win,
                                float* __restrict__ out)
{
    long i = (long)blockIdx.x * 256 + threadIdx.x;
    if (i < 4194304) out[i] = x[i];
    else if (i < 4194308) out[i] = win[i - 4194304];
}

// ---------------------------------------------------------------------------
extern "C" void kernel_launch(void* const* d_in, const int* in_sizes, int n_in,
                              void* d_out, int out_size, void* d_ws, size_t ws_size,
                              hipStream_t stream)
{
    (void)in_sizes; (void)n_in; (void)out_size; (void)ws_size;
    const float* patches = (const float*)d_in[0];
    const float* embed_w = (const float*)d_in[1];
    const float* embed_b = (const float*)d_in[2];
    const float* bd_w1 = (const float*)d_in[3];
    const float* bd_b1 = (const float*)d_in[4];
    const float* bd_w2 = (const float*)d_in[5];
    const float* bd_b2 = (const float*)d_in[6];
    const float* bd_w3 = (const float*)d_in[7];
    const float* bd_b3 = (const float*)d_in[8];
    const float* norm_g = (const float*)d_in[9];
    const float* qkv_w = (const float*)d_in[10];
    const float* qkv_b = (const float*)d_in[11];
    const float* out_w = (const float*)d_in[12];
    const float* out_b = (const float*)d_in[13];
    const float* gate_w = (const float*)d_in[14];
    const float* gate_b = (const float*)d_in[15];

    char* p = (char*)d_ws;
    auto alloc = [&](size_t bytes) { char* r = p; p += (bytes + 255) & ~(size_t)255; return r; };
    unsigned short* WQ   = (unsigned short*)alloc(3ll * 3072 * 1024 * 2);
    unsigned short* WO   = (unsigned short*)alloc(3ll * 1024 * 1024 * 2);
    unsigned short* WG   = (unsigned short*)alloc(3ll * 1024 * 1024 * 2);
    unsigned short* W1T  = (unsigned short*)alloc(512ll * 5120 * 2);
    unsigned short* W2T  = (unsigned short*)alloc(256ll * 1536 * 2);
    unsigned short* XPAD = (unsigned short*)alloc(4ll * 1028 * 1024 * 2);
    unsigned short* H1P  = (unsigned short*)alloc(4ll * 1026 * 512 * 2);
    unsigned short* H2   = (unsigned short*)alloc(4ll * 1024 * 256 * 2);
    float*          X    = (float*)alloc(4ll * 1024 * 1024 * 4);
    unsigned short* HN   = (unsigned short*)alloc(4096ll * 1024 * 2);
    unsigned short* QKV  = (unsigned short*)alloc(4096ll * 3072 * 2);
    unsigned short* YATT = (unsigned short*)alloc(4096ll * 1024 * 2);
    float*          YBUF = (float*)alloc(4096ll * 1024 * 4);
    float*          LOGI = (float*)alloc(4096 * 4);
    float*          ROPE = (float*)alloc(65536 * 4);
    float*          WIN  = (float*)alloc(256);

    hipMemsetAsync(XPAD, 0, 4ll * 1028 * 1024 * 2, stream);
    hipMemsetAsync(H1P, 0, 4ll * 1026 * 512 * 2, stream);

    wtrans_kernel<<<dim3(96, 32, 3), 256, 0, stream>>>(qkv_w, WQ, 1024, 3072);
    wtrans_kernel<<<dim3(32, 32, 3), 256, 0, stream>>>(out_w, WO, 1024, 1024);
    wtrans_kernel<<<dim3(32, 32, 3), 256, 0, stream>>>(gate_w, WG, 1024, 1024);
    wconv_trans_kernel<<<10240, 256, 0, stream>>>(bd_w1, W1T, 1024, 5, 512ll * 5120);
    wconv_trans_kernel<<<1536, 256, 0, stream>>>(bd_w2, W2T, 512, 3, 256ll * 1536);
    rope_table_kernel<<<128, 256, 0, stream>>>(ROPE);
    embed_kernel<<<512, 1024, 0, stream>>>(patches, embed_w, embed_b, X, XPAD);

    // conv1 as GEMM: A = xpad (lda=1024 < K=5120 gives the im2col overlap)
    gemm_bt<1><<<dim3(4, 8, 4), 256, 0, stream>>>(XPAD, 1028ll * 1024, 1024, W1T, bd_b1, 5120,
                                                  H1P + 512, 1026ll * 512, 512, nullptr, nullptr);
    // conv2 as GEMM
    gemm_bt<1><<<dim3(2, 8, 4), 256, 0, stream>>>(H1P, 1026ll * 512, 512, W2T, bd_b2, 1536,
                                                  H2, 1024ll * 256, 256, nullptr, nullptr);
    conv3_kernel<<<1024, 256, 0, stream>>>(H2, bd_w3, bd_b3, LOGI);
    winmax_kernel<<<4, 256, 0, stream>>>(LOGI, WIN);

    for (int l = 0; l < 3; l++) {
        zcrms_kernel<<<4096, 256, 0, stream>>>(X, norm_g + l * 1024, HN);
        gemm_bt<0><<<dim3(24, 32, 1), 256, 0, stream>>>(HN, 0, 1024, WQ + (long)l * 3072 * 1024,
                                                        qkv_b + l * 3072, 1024, QKV, 0, 3072,
                                                        nullptr, nullptr);
        rope_kernel<<<16384, 256, 0, stream>>>(QKV, ROPE);
        attn_kernel<<<dim3(16, 64), 256, 0, stream>>>(QKV, LOGI, YATT);
        gemm_bt<2><<<dim3(8, 32, 1), 256, 0, stream>>>(YATT, 0, 1024, WO + (long)l * 1024 * 1024,
                                                       out_b + l * 1024, 1024, nullptr, 0, 1024,
                                                       YBUF, nullptr);
        gemm_bt<3><<<dim3(8, 32, 1), 256, 0, stream>>>(HN, 0, 1024, WG + (long)l * 1024 * 1024,
                                                       gate_b + l * 1024, 1024, nullptr, 0, 0,
                                                       X, YBUF);
    }
    finalize_kernel<<<16387, 256, 0, stream>>>(X, WIN, (float*)d_out);
}

// Round 2
// 799.170 us; speedup vs baseline: 1.2213x; 1.2213x over previous
//
#include <hip/hip_runtime.h>
#include <stdint.h>
#include <math.h>

typedef __attribute__((ext_vector_type(8))) short short8;
typedef __attribute__((ext_vector_type(4))) float f32x4;
typedef __attribute__((ext_vector_type(16))) float f32x16;

__device__ __forceinline__ float b2f(unsigned short u) {
    union { unsigned int i; float f; } v; v.i = ((unsigned int)u) << 16; return v.f;
}
__device__ __forceinline__ unsigned short f2b(float f) {
    union { float f; unsigned int i; } v; v.f = f;
    unsigned int r = v.i + 0x7fffu + ((v.i >> 16) & 1u);
    return (unsigned short)(r >> 16);
}

__device__ __forceinline__ void gload_lds16(const void* g, void* l) {
    __builtin_amdgcn_global_load_lds((__attribute__((address_space(1))) void*)g,
                                     (__attribute__((address_space(3))) void*)l,
                                     16, 0, 0);
}

// ---------------------------------------------------------------------------
// Generic bf16 MFMA GEMM: C[row][col] = sum_k A[row*lda + k] * Bw[col*K + k]
// 128x128 tile, BK=32, 4 waves, 4x4 16x16x32 frags per wave.
// EPI: 0 bias+bf16; 1 bias+silu+bf16; 2 bias+f32; 3 bias+sigmoid*Yin += Cf
// ---------------------------------------------------------------------------
template<int EPI>
__global__ __launch_bounds__(256)
void gemm_bt(const unsigned short* __restrict__ A, long sAb, int lda,
             const unsigned short* __restrict__ Bw,
             const float* __restrict__ bias, int K,
             unsigned short* __restrict__ Cb, long sCb, int ldc,
             float* __restrict__ Cf, const float* __restrict__ Yin)
{
    __shared__ __align__(16) unsigned short As[128 * 32];
    __shared__ __align__(16) unsigned short Bs[128 * 32];
    const int tid = threadIdx.x;
    const int lane = tid & 63, wid = tid >> 6;
    const int wr = wid >> 1, wc = wid & 1;
    const int z = blockIdx.z;
    const long brow = (long)blockIdx.y * 128;
    const long bcol = (long)blockIdx.x * 128;
    const unsigned short* Ab = A + (long)z * sAb;

    const int arow = tid >> 2;          // 0..63
    const int acol = (tid & 3) * 8;
    const unsigned short* ga0 = Ab + (brow + arow) * (long)lda + acol;
    const unsigned short* ga1 = Ab + (brow + 64 + arow) * (long)lda + acol;
    const unsigned short* gb0 = Bw + (bcol + arow) * (long)K + acol;
    const unsigned short* gb1 = Bw + (bcol + 64 + arow) * (long)K + acol;
    unsigned short* la0 = As + wid * 512;
    unsigned short* la1 = As + 2048 + wid * 512;
    unsigned short* lb0 = Bs + wid * 512;
    unsigned short* lb1 = Bs + 2048 + wid * 512;

    f32x4 acc[4][4] = {};

    for (int kk = 0; kk < K; kk += 32) {
        gload_lds16(ga0 + kk, la0);
        gload_lds16(ga1 + kk, la1);
        gload_lds16(gb0 + kk, lb0);
        gload_lds16(gb1 + kk, lb1);
        __syncthreads();
        const int fr = lane & 15, fk = (lane >> 4) * 8;
        short8 af[4], bfrag[4];
#pragma unroll
        for (int m = 0; m < 4; m++)
            af[m] = *(const short8*)(As + (wr * 64 + m * 16 + fr) * 32 + fk);
#pragma unroll
        for (int n = 0; n < 4; n++)
            bfrag[n] = *(const short8*)(Bs + (wc * 64 + n * 16 + fr) * 32 + fk);
#pragma unroll
        for (int m = 0; m < 4; m++)
#pragma unroll
            for (int n = 0; n < 4; n++)
                acc[m][n] = __builtin_amdgcn_mfma_f32_16x16x32_bf16(af[m], bfrag[n], acc[m][n], 0, 0, 0);
        __syncthreads();
    }

    const int fr = lane & 15;
    const int fq = (lane >> 4) * 4;
#pragma unroll
    for (int m = 0; m < 4; m++) {
#pragma unroll
        for (int n = 0; n < 4; n++) {
#pragma unroll
            for (int j = 0; j < 4; j++) {
                long row = brow + wr * 64 + m * 16 + fq + j;
                long col = bcol + wc * 64 + n * 16 + fr;
                float v = acc[m][n][j] + bias[col];
                if (EPI == 0) {
                    Cb[z * sCb + row * ldc + col] = f2b(v);
                } else if (EPI == 1) {
                    float sg = 1.f / (1.f + expf(-v));
                    Cb[z * sCb + row * ldc + col] = f2b(v * sg);
                } else if (EPI == 2) {
                    Cf[row * ldc + col] = v;
                } else {
                    float sg = 1.f / (1.f + expf(-v));
                    long idx = row * 1024 + col;
                    Cf[idx] += sg * Yin[idx];
                }
            }
        }
    }
}

// ---------------------------------------------------------------------------
// V transpose: VT[b][h][d][n] = V[b][n][h][d]   (64 n x 64 d tiles)
// ---------------------------------------------------------------------------
__global__ __launch_bounds__(256)
void vtrans_kernel(const unsigned short* __restrict__ qkv, unsigned short* __restrict__ vt)
{
    __shared__ unsigned short sm[64][72];
    const int nt = blockIdx.x, bh = blockIdx.y;
    const int b = bh >> 4, h = bh & 15;
    const int tid = threadIdx.x;
    const unsigned short* vsrc = qkv + ((long)b * 1024 + nt * 64) * 3072 + 2048 + h * 64;
    const int r = tid >> 2, c0 = (tid & 3) * 16;
#pragma unroll
    for (int t = 0; t < 2; t++) {
        short8 v = *(const short8*)(vsrc + (long)r * 3072 + c0 + t * 8);
        *(short8*)(&sm[r][c0 + t * 8]) = v;
    }
    __syncthreads();
    const int d = tid >> 2, n0 = (tid & 3) * 16;
    unsigned short tmp[16];
#pragma unroll
    for (int i = 0; i < 16; i++) tmp[i] = sm[n0 + i][d];
    unsigned short* dst = vt + ((long)bh * 64 + d) * 1024 + nt * 64 + n0;
    *(short8*)(dst) = *(const short8*)(tmp);
    *(short8*)(dst + 8) = *(const short8*)(tmp + 8);
}

// ---------------------------------------------------------------------------
// Flash attention, swapped-QK^T 32x32 structure.
// grid (8 qtiles, 64 bh) x 256 thr. Wave w owns q rows qt*128 + w*32 .. +32.
// S[key][q] via mfma(K,Q): q = lane&31 (lane-local softmax), key = row(r,hh).
// P redistributed across the 32-lane halves via shfl_xor(32).
// V read as pre-transposed VT[bh][d][n] (global, L2-resident). No LDS in loop.
// ---------------------------------------------------------------------------
__global__ __launch_bounds__(256)
void attn_kernel(const unsigned short* __restrict__ qkv,
                 const unsigned short* __restrict__ vt,
                 const float* __restrict__ plog,
                 unsigned short* __restrict__ y)
{
    __shared__ float pl[1024];
    const int qt = blockIdx.x;
    const int bh = blockIdx.y;
    const int b = bh >> 4, h = bh & 15;
    const int tid = threadIdx.x, lane = tid & 63, wid = tid >> 6;
    const int c = lane & 31;
    const int hh = lane >> 5;

    const long nb = (long)b * 1024;
    const unsigned short* qbase = qkv + nb * 3072 + h * 64;
    const unsigned short* kbase = qbase + 1024;
    const unsigned short* vtb = vt + (long)bh * 65536;

    for (int i = tid; i < 1024; i += 256) pl[i] = plog[b * 1024 + i];
    __syncthreads();

    const int q0 = qt * 128 + wid * 32;
    short8 qf[4];
#pragma unroll
    for (int d = 0; d < 4; d++)
        qf[d] = *(const short8*)(qbase + (long)(q0 + c) * 3072 + d * 16 + hh * 8);

    float m_run = -1e30f, l_run = 0.f;
    f32x16 o0 = {}, o1 = {};

    const unsigned short* kp = kbase + (long)c * 3072 + hh * 8;
    const unsigned short* vp = vtb + (long)c * 1024 + hh * 8;

    short8 kf[4], vf[4];
#pragma unroll
    for (int d = 0; d < 4; d++) kf[d] = *(const short8*)(kp + d * 16);
#pragma unroll
    for (int n2 = 0; n2 < 2; n2++)
#pragma unroll
        for (int kh = 0; kh < 2; kh++)
            vf[n2 * 2 + kh] = *(const short8*)(vp + n2 * 32768 + kh * 16);

    for (int kt = 0; kt < 1024; kt += 32) {
        // QK^T (swapped): s[key][q], col q = lane&31
        f32x16 s = {};
#pragma unroll
        for (int d = 0; d < 4; d++)
            s = __builtin_amdgcn_mfma_f32_32x32x16_bf16(kf[d], qf[d], s, 0, 0, 0);

        // prefetch next tile's K and VT fragments (no barriers in loop)
        short8 kn[4], vn[4];
        const bool more = (kt + 32) < 1024;
        if (more) {
#pragma unroll
            for (int d = 0; d < 4; d++)
                kn[d] = *(const short8*)(kp + (long)(kt + 32) * 3072 + d * 16);
#pragma unroll
            for (int n2 = 0; n2 < 2; n2++)
#pragma unroll
                for (int kh = 0; kh < 2; kh++)
                    vn[n2 * 2 + kh] = *(const short8*)(vp + n2 * 32768 + (kt + 32) + kh * 16);
        }

        // scale + column bias; per-lane max over own 16 keys of q = c
        float mx = -1e30f;
#pragma unroll
        for (int r = 0; r < 16; r++) {
            int key = (r & 3) + 8 * (r >> 2) + 4 * hh;
            float pv = s[r] * 0.125f + pl[kt + key];
            s[r] = pv;
            mx = fmaxf(mx, pv);
        }
        mx = fmaxf(mx, __shfl_xor(mx, 32));

        // defer-max (T13): only rescale when tile max exceeds m_run + 8
        if (!__all(mx - m_run <= 8.f)) {
            float mnew = fmaxf(m_run, mx);
            float f = __expf(m_run - mnew);
            l_run *= f;
#pragma unroll
            for (int r = 0; r < 16; r++) {
                int qrow = (r & 3) + 8 * (r >> 2) + 4 * hh;
                float fr = __shfl(f, qrow);
                o0[r] *= fr;
                o1[r] *= fr;
            }
            m_run = mnew;
        }

        // exponentials + bf16 pack (pairs) + running denominator
        float sum = 0.f;
        unsigned int pk[8];
#pragma unroll
        for (int bb = 0; bb < 4; bb++) {
#pragma unroll
            for (int t = 0; t < 2; t++) {
                float e0 = __expf(s[bb * 4 + 2 * t] - m_run);
                float e1 = __expf(s[bb * 4 + 2 * t + 1] - m_run);
                sum += e0 + e1;
                pk[bb * 2 + t] = (unsigned int)f2b(e0) | ((unsigned int)f2b(e1) << 16);
            }
        }
        sum += __shfl_xor(sum, 32);
        l_run += sum;

        // redistribute P across the 32-lane halves -> PV A-fragments
        unsigned int sx0 = (unsigned int)__shfl_xor((int)pk[0], 32);
        unsigned int sx1 = (unsigned int)__shfl_xor((int)pk[1], 32);
        unsigned int sx2 = (unsigned int)__shfl_xor((int)pk[2], 32);
        unsigned int sx3 = (unsigned int)__shfl_xor((int)pk[3], 32);
        unsigned int sx4 = (unsigned int)__shfl_xor((int)pk[4], 32);
        unsigned int sx5 = (unsigned int)__shfl_xor((int)pk[5], 32);
        unsigned int sx6 = (unsigned int)__shfl_xor((int)pk[6], 32);
        unsigned int sx7 = (unsigned int)__shfl_xor((int)pk[7], 32);
        union U8 { unsigned int u[4]; short8 v; } A0, A1;
        A0.u[0] = hh ? sx2 : pk[0];
        A0.u[1] = hh ? sx3 : pk[1];
        A0.u[2] = hh ? pk[2] : sx0;
        A0.u[3] = hh ? pk[3] : sx1;
        A1.u[0] = hh ? sx6 : pk[4];
        A1.u[1] = hh ? sx7 : pk[5];
        A1.u[2] = hh ? pk[6] : sx4;
        A1.u[3] = hh ? pk[7] : sx5;

        // PV: o[q][d] += P[q][k] * V[k][d]
        o0 = __builtin_amdgcn_mfma_f32_32x32x16_bf16(A0.v, vf[0], o0, 0, 0, 0);
        o0 = __builtin_amdgcn_mfma_f32_32x32x16_bf16(A1.v, vf[1], o0, 0, 0, 0);
        o1 = __builtin_amdgcn_mfma_f32_32x32x16_bf16(A0.v, vf[2], o1, 0, 0, 0);
        o1 = __builtin_amdgcn_mfma_f32_32x32x16_bf16(A1.v, vf[3], o1, 0, 0, 0);

        if (more) {
#pragma unroll
            for (int d = 0; d < 4; d++) kf[d] = kn[d];
#pragma unroll
            for (int i = 0; i < 4; i++) vf[i] = vn[i];
        }
    }

    // epilogue: normalize rows and store
#pragma unroll
    for (int r = 0; r < 16; r++) {
        int qrow = (r & 3) + 8 * (r >> 2) + 4 * hh;
        float lr = __shfl(l_run, qrow);
        float inv = 1.f / lr;
        long row = nb + q0 + qrow;
        y[row * 1024 + h * 64 + c] = f2b(o0[r] * inv);
        y[row * 1024 + h * 64 + 32 + c] = f2b(o1[r] * inv);
    }
}

// --------------------------------------------------------------------------
__global__ __launch_bounds__(256)
void zcrms_kernel(const float* __restrict__ x, const float* __restrict__ g,
                  unsigned short* __restrict__ hn)
{
    __shared__ float red[8];
    const long row = blockIdx.x;
    const int tid = threadIdx.x;
    const float* xr = x + row * 1024;
    float4 v = *(const float4*)(xr + tid * 4);
    float s = v.x + v.y + v.z + v.w;
#pragma unroll
    for (int m = 32; m; m >>= 1) s += __shfl_xor(s, m);
    const int lane = tid & 63, wid = tid >> 6;
    if (lane == 0) red[wid] = s;
    __syncthreads();
    float mean = (red[0] + red[1] + red[2] + red[3]) * (1.f / 1024.f);
    float c0 = v.x - mean, c1 = v.y - mean, c2 = v.z - mean, c3 = v.w - mean;
    float s2 = c0 * c0 + c1 * c1 + c2 * c2 + c3 * c3;
#pragma unroll
    for (int m = 32; m; m >>= 1) s2 += __shfl_xor(s2, m);
    if (lane == 0) red[4 + wid] = s2;
    __syncthreads();
    float rinv = rsqrtf((red[4] + red[5] + red[6] + red[7]) * (1.f / 1024.f) + 1e-8f);
    const float* gr = g + tid * 4;
    unsigned int lo = (unsigned int)f2b(c0 * rinv * gr[0]) | ((unsigned int)f2b(c1 * rinv * gr[1]) << 16);
    unsigned int hi = (unsigned int)f2b(c2 * rinv * gr[2]) | ((unsigned int)f2b(c3 * rinv * gr[3]) << 16);
    uint2 u; u.x = lo; u.y = hi;
    *(uint2*)(hn + row * 1024 + tid * 4) = u;
}

__global__ __launch_bounds__(1024)
void embed_kernel(const float* __restrict__ patches, const float* __restrict__ W,
                  const float* __restrict__ bias, float* __restrict__ x,
                  unsigned short* __restrict__ xpad)
{
    __shared__ float sp[8][75];
    const long r0 = (long)blockIdx.x * 8;
    const int tid = threadIdx.x;
    for (int i = tid; i < 600; i += 1024) sp[i / 75][i % 75] = patches[r0 * 75 + i];
    __syncthreads();
    float acc[8];
    float bb = bias[tid];
#pragma unroll
    for (int j = 0; j < 8; j++) acc[j] = bb;
    for (int p = 0; p < 75; p++) {
        float w = W[p * 1024 + tid];
#pragma unroll
        for (int j = 0; j < 8; j++) acc[j] += sp[j][p] * w;
    }
#pragma unroll
    for (int j = 0; j < 8; j++) {
        long r = r0 + j;
        x[r * 1024 + tid] = acc[j];
        long bb2 = r >> 10, n = r & 1023;
        xpad[(bb2 * 1028 + n + 2) * 1024 + tid] = f2b(acc[j]);
    }
}

__global__ void rope_table_kernel(float* __restrict__ tab)
{
    int idx = blockIdx.x * 256 + threadIdx.x;   // 32768
    int n = idx >> 5, i = idx & 31;
    float inv = powf(10000.0f, -(float)i * (1.0f / 32.0f));
    float ang = (float)n * inv;
    tab[idx] = cosf(ang);
    tab[32768 + idx] = sinf(ang);
}

__global__ void rope_kernel(unsigned short* __restrict__ qkv, const float* __restrict__ tab)
{
    long idx = (long)blockIdx.x * 256 + threadIdx.x;   // 4194304
    int i = (int)(idx & 31);
    int h = (int)((idx >> 5) & 15);
    int w2 = (int)((idx >> 9) & 1);
    int n = (int)((idx >> 10) & 1023);
    int b = (int)(idx >> 20);
    long base = ((long)((b * 1024 + n) * 3 + w2)) * 1024 + h * 64 + 2 * i;
    float x0 = b2f(qkv[base]);
    float x1 = b2f(qkv[base + 1]);
    float cc = tab[n * 32 + i], sn = tab[32768 + n * 32 + i];
    qkv[base] = f2b(x0 * cc - x1 * sn);
    qkv[base + 1] = f2b(x0 * sn + x1 * cc);
}

__global__ __launch_bounds__(256)
void conv3_kernel(const unsigned short* __restrict__ h2, const float* __restrict__ w3,
                  const float* __restrict__ b3, float* __restrict__ logits)
{
    const long row = (long)blockIdx.x * 4 + (threadIdx.x >> 6);
    const int lane = threadIdx.x & 63;
    const unsigned short* hr = h2 + row * 256;
    float s = 0.f;
#pragma unroll
    for (int t = 0; t < 4; t++) s += b2f(hr[lane + t * 64]) * w3[lane + t * 64];
#pragma unroll
    for (int m = 32; m; m >>= 1) s += __shfl_xor(s, m);
    if (lane == 0) logits[row] = s + b3[0];
}

__global__ __launch_bounds__(256)
void winmax_kernel(const float* __restrict__ logits, float* __restrict__ win)
{
    __shared__ float red[4];
    const int b = blockIdx.x, tid = threadIdx.x;
    float m = -1e30f;
    for (int i = tid; i < 1024; i += 256) m = fmaxf(m, logits[b * 1024 + i]);
#pragma unroll
    for (int k = 32; k; k >>= 1) m = fmaxf(m, __shfl_xor(m, k));
    if ((tid & 63) == 0) red[tid >> 6] = m;
    __syncthreads();
    if (tid == 0) win[b] = fmaxf(fmaxf(red[0], red[1]), fmaxf(red[2], red[3]));
}

// f32 (K,Nc) -> bf16 (Nc,K), batched over z
__global__ __launch_bounds__(256)
void wtrans_kernel(const float* __restrict__ in, unsigned short* __restrict__ out,
                   int K, int Nc)
{
    __shared__ float tile[32][33];
    const long base = (long)blockIdx.z * K * Nc;
    const int k0 = blockIdx.y * 32, n0 = blockIdx.x * 32;
    const int tx = threadIdx.x & 31, ty = threadIdx.x >> 5;
#pragma unroll
    for (int r = ty; r < 32; r += 8) tile[r][tx] = in[base + (long)(k0 + r) * Nc + n0 + tx];
    __syncthreads();
#pragma unroll
    for (int r = ty; r < 32; r += 8) out[base + (long)(n0 + r) * K + k0 + tx] = f2b(tile[tx][r]);
}

// (Co,Ci,Kw) f32 -> (Co, Kw*Ci) bf16 with k = dk*Ci + ci
__global__ void wconv_trans_kernel(const float* __restrict__ in, unsigned short* __restrict__ out,
                                   int Ci, int Kw, long total)
{
    long idx = (long)blockIdx.x * 256 + threadIdx.x;
    if (idx >= total) return;
    long ck = (long)Ci * Kw;
    int co = (int)(idx / ck);
    int rem = (int)(idx % ck);
    int dk = rem / Ci, ci = rem % Ci;
    out[idx] = f2b(in[(long)co * ck + (long)ci * Kw + dk]);
}

__global__ void finalize_kernel(const float* __restrict__ x, const float* __restrict__ win,
                                float* __restrict__ out)
{
    long i = (long)blockIdx.x * 256 + threadIdx.x;
    if (i < 4194304) out[i] = x[i];
    else if (i < 4194308) out[i] = win[i - 4194304];
}

// ---------------------------------------------------------------------------
extern "C" void kernel_launch(void* const* d_in, const int* in_sizes, int n_in,
                              void* d_out, int out_size, void* d_ws, size_t ws_size,
                              hipStream_t stream)
{
    (void)in_sizes; (void)n_in; (void)out_size; (void)ws_size;
    const float* patches = (const float*)d_in[0];
    const float* embed_w = (const float*)d_in[1];
    const float* embed_b = (const float*)d_in[2];
    const float* bd_w1 = (const float*)d_in[3];
    const float* bd_b1 = (const float*)d_in[4];
    const float* bd_w2 = (const float*)d_in[5];
    const float* bd_b2 = (const float*)d_in[6];
    const float* bd_w3 = (const float*)d_in[7];
    const float* bd_b3 = (const float*)d_in[8];
    const float* norm_g = (const float*)d_in[9];
    const float* qkv_w = (const float*)d_in[10];
    const float* qkv_b = (const float*)d_in[11];
    const float* out_w = (const float*)d_in[12];
    const float* out_b = (const float*)d_in[13];
    const float* gate_w = (const float*)d_in[14];
    const float* gate_b = (const float*)d_in[15];

    char* p = (char*)d_ws;
    auto alloc = [&](size_t bytes) { char* r = p; p += (bytes + 255) & ~(size_t)255; return r; };
    unsigned short* WQ   = (unsigned short*)alloc(3ll * 3072 * 1024 * 2);
    unsigned short* WO   = (unsigned short*)alloc(3ll * 1024 * 1024 * 2);
    unsigned short* WG   = (unsigned short*)alloc(3ll * 1024 * 1024 * 2);
    unsigned short* W1T  = (unsigned short*)alloc(512ll * 5120 * 2);
    unsigned short* W2T  = (unsigned short*)alloc(256ll * 1536 * 2);
    unsigned short* XPAD = (unsigned short*)alloc(4ll * 1028 * 1024 * 2);
    unsigned short* H1P  = (unsigned short*)alloc(4ll * 1026 * 512 * 2);
    unsigned short* H2   = (unsigned short*)alloc(4ll * 1024 * 256 * 2);
    float*          X    = (float*)alloc(4ll * 1024 * 1024 * 4);
    unsigned short* HN   = (unsigned short*)alloc(4096ll * 1024 * 2);
    unsigned short* QKV  = (unsigned short*)alloc(4096ll * 3072 * 2);
    unsigned short* YATT = (unsigned short*)alloc(4096ll * 1024 * 2);
    float*          YBUF = (float*)alloc(4096ll * 1024 * 4);
    float*          LOGI = (float*)alloc(4096 * 4);
    float*          ROPE = (float*)alloc(65536 * 4);
    float*          WIN  = (float*)alloc(256);
    // VT (B,H,64,1024) bf16 = 8MB aliased onto XPAD (conv pipeline is done
    // before the first attention layer runs)
    unsigned short* VT   = XPAD;

    hipMemsetAsync(XPAD, 0, 4ll * 1028 * 1024 * 2, stream);
    hipMemsetAsync(H1P, 0, 4ll * 1026 * 512 * 2, stream);

    wtrans_kernel<<<dim3(96, 32, 3), 256, 0, stream>>>(qkv_w, WQ, 1024, 3072);
    wtrans_kernel<<<dim3(32, 32, 3), 256, 0, stream>>>(out_w, WO, 1024, 1024);
    wtrans_kernel<<<dim3(32, 32, 3), 256, 0, stream>>>(gate_w, WG, 1024, 1024);
    wconv_trans_kernel<<<10240, 256, 0, stream>>>(bd_w1, W1T, 1024, 5, 512ll * 5120);
    wconv_trans_kernel<<<1536, 256, 0, stream>>>(bd_w2, W2T, 512, 3, 256ll * 1536);
    rope_table_kernel<<<128, 256, 0, stream>>>(ROPE);
    embed_kernel<<<512, 1024, 0, stream>>>(patches, embed_w, embed_b, X, XPAD);

    // conv1 as GEMM: A = xpad (lda=1024 < K=5120 gives the im2col overlap)
    gemm_bt<1><<<dim3(4, 8, 4), 256, 0, stream>>>(XPAD, 1028ll * 1024, 1024, W1T, bd_b1, 5120,
                                                  H1P + 512, 1026ll * 512, 512, nullptr, nullptr);
    // conv2 as GEMM
    gemm_bt<1><<<dim3(2, 8, 4), 256, 0, stream>>>(H1P, 1026ll * 512, 512, W2T, bd_b2, 1536,
                                                  H2, 1024ll * 256, 256, nullptr, nullptr);
    conv3_kernel<<<1024, 256, 0, stream>>>(H2, bd_w3, bd_b3, LOGI);
    winmax_kernel<<<4, 256, 0, stream>>>(LOGI, WIN);

    for (int l = 0; l < 3; l++) {
        zcrms_kernel<<<4096, 256, 0, stream>>>(X, norm_g + l * 1024, HN);
        gemm_bt<0><<<dim3(24, 32, 1), 256, 0, stream>>>(HN, 0, 1024, WQ + (long)l * 3072 * 1024,
                                                        qkv_b + l * 3072, 1024, QKV, 0, 3072,
                                                        nullptr, nullptr);
        vtrans_kernel<<<dim3(16, 64), 256, 0, stream>>>(QKV, VT);
        rope_kernel<<<16384, 256, 0, stream>>>(QKV, ROPE);
        attn_kernel<<<dim3(8, 64), 256, 0, stream>>>(QKV, VT, LOGI, YATT);
        gemm_bt<2><<<dim3(8, 32, 1), 256, 0, stream>>>(YATT, 0, 1024, WO + (long)l * 1024 * 1024,
                                                       out_b + l * 1024, 1024, nullptr, 0, 1024,
                                                       YBUF, nullptr);
        gemm_bt<3><<<dim3(8, 32, 1), 256, 0, stream>>>(HN, 0, 1024, WG + (long)l * 1024 * 1024,
                                                       gate_b + l * 1024, 1024, nullptr, 0, 0,
                                                       X, YBUF);
    }
    finalize_kernel<<<16387, 256, 0, stream>>>(X, WIN, (float*)d_out);
}

// Round 3
// 605.436 us; speedup vs baseline: 1.6120x; 1.3200x over previous
//
#include <hip/hip_runtime.h>
#include <stdint.h>
#include <math.h>

typedef __attribute__((ext_vector_type(8))) short short8;
typedef __attribute__((ext_vector_type(4))) float f32x4;
typedef __attribute__((ext_vector_type(16))) float f32x16;

__device__ __forceinline__ float b2f(unsigned short u) {
    union { unsigned int i; float f; } v; v.i = ((unsigned int)u) << 16; return v.f;
}
__device__ __forceinline__ unsigned short f2b(float f) {
    union { float f; unsigned int i; } v; v.f = f;
    unsigned int r = v.i + 0x7fffu + ((v.i >> 16) & 1u);
    return (unsigned short)(r >> 16);
}

__device__ __forceinline__ void gload_lds16(const void* g, void* l) {
    __builtin_amdgcn_global_load_lds((__attribute__((address_space(1))) void*)g,
                                     (__attribute__((address_space(3))) void*)l,
                                     16, 0, 0);
}

// ---------------------------------------------------------------------------
// qkv GEMM with fused RoPE epilogue.
// C[row][col] = A[row]·Bw[col] + bias[col], rope applied to cols < 2048.
// A: (4096,1024) bf16, Bw: (3072,1024) bf16 K-contig, C: (4096,3072) bf16.
// ---------------------------------------------------------------------------
__global__ __launch_bounds__(256)
void qkv_gemm(const unsigned short* __restrict__ A,
              const unsigned short* __restrict__ Bw,
              const float* __restrict__ bias,
              unsigned short* __restrict__ Cb,
              const float* __restrict__ rope)
{
    __shared__ __align__(16) unsigned short As[128 * 32];
    __shared__ __align__(16) unsigned short Bs[128 * 32];
    const int tid = threadIdx.x;
    const int lane = tid & 63, wid = tid >> 6;
    const int wr = wid >> 1, wc = wid & 1;
    const long brow = (long)blockIdx.y * 128;
    const long bcol = (long)blockIdx.x * 128;

    const int arow = tid >> 2;
    const int acol = (tid & 3) * 8;
    const unsigned short* ga0 = A + (brow + arow) * 1024 + acol;
    const unsigned short* ga1 = A + (brow + 64 + arow) * 1024 + acol;
    const unsigned short* gb0 = Bw + (bcol + arow) * 1024 + acol;
    const unsigned short* gb1 = Bw + (bcol + 64 + arow) * 1024 + acol;
    unsigned short* la0 = As + wid * 512;
    unsigned short* la1 = As + 2048 + wid * 512;
    unsigned short* lb0 = Bs + wid * 512;
    unsigned short* lb1 = Bs + 2048 + wid * 512;

    f32x4 acc[4][4] = {};

    for (int kk = 0; kk < 1024; kk += 32) {
        gload_lds16(ga0 + kk, la0);
        gload_lds16(ga1 + kk, la1);
        gload_lds16(gb0 + kk, lb0);
        gload_lds16(gb1 + kk, lb1);
        __syncthreads();
        const int fr = lane & 15, fk = (lane >> 4) * 8;
        short8 af[4], bfrag[4];
#pragma unroll
        for (int m = 0; m < 4; m++)
            af[m] = *(const short8*)(As + (wr * 64 + m * 16 + fr) * 32 + fk);
#pragma unroll
        for (int n = 0; n < 4; n++)
            bfrag[n] = *(const short8*)(Bs + (wc * 64 + n * 16 + fr) * 32 + fk);
#pragma unroll
        for (int m = 0; m < 4; m++)
#pragma unroll
            for (int n = 0; n < 4; n++)
                acc[m][n] = __builtin_amdgcn_mfma_f32_16x16x32_bf16(af[m], bfrag[n], acc[m][n], 0, 0, 0);
        __syncthreads();
    }

    const int fr = lane & 15;
    const int fq = (lane >> 4) * 4;
#pragma unroll
    for (int m = 0; m < 4; m++) {
#pragma unroll
        for (int n = 0; n < 4; n++) {
#pragma unroll
            for (int j = 0; j < 4; j++) {
                long row = brow + wr * 64 + m * 16 + fq + j;
                int col = (int)bcol + wc * 64 + n * 16 + fr;
                float v = acc[m][n][j] + bias[col];
                float part = __shfl_xor(v, 1);   // partner col (d^1), same row
                if (col < 2048) {
                    int d = col & 63;
                    int i2 = d >> 1;
                    int ntok = (int)(row & 1023);
                    float cc = rope[ntok * 32 + i2];
                    float ss = rope[32768 + ntok * 32 + i2];
                    v = (d & 1) ? (part * ss + v * cc) : (v * cc - part * ss);
                }
                Cb[row * 3072 + col] = f2b(v);
            }
        }
    }
}

// ---------------------------------------------------------------------------
// Tap-accumulation conv-as-GEMM. Output tile 128 rows x 64 out-ch, 4 waves
// (each 64r x 32c, 4x2 frags). A staged ONCE (144 rows incl. tap overlap),
// per-tap weight tiles; MFMA reads A at row+dk. 2-phase double-buffered.
// A: padded input, row stride CI, batch stride sAb. Bw: [dk][co][ci].
// Epilogue: silu, bf16 store at (crow_off + row).
// ---------------------------------------------------------------------------
template<int KW, int CI>
__global__ __launch_bounds__(256)
void conv_gemm(const unsigned short* __restrict__ A, long sAb,
               const unsigned short* __restrict__ Bw, int CO,
               const float* __restrict__ bias,
               unsigned short* __restrict__ C, long sCb, int ldc, int crow_off)
{
    __shared__ __align__(16) unsigned short As[2][144 * 32];
    __shared__ __align__(16) unsigned short Bs[2][KW * 64 * 32];
    const int tid = threadIdx.x, lane = tid & 63, wid = tid >> 6;
    const int wr = wid >> 1, wc = wid & 1;
    const int z = blockIdx.z;
    const long brow = (long)blockIdx.y * 128;
    const long bcol = (long)blockIdx.x * 64;
    const unsigned short* Ab = A + z * sAb + brow * CI;
    const int srow = tid >> 2, scol = (tid & 3) * 8;

    f32x4 acc[4][2] = {};

    auto STAGE = [&](int buf, int kk) {
#pragma unroll
        for (int o = 0; o < 2; o++)
            gload_lds16(Ab + (long)(o * 64 + srow) * CI + kk + scol,
                        As[buf] + (o * 64 + wid * 16) * 32);
        if (wid == 0)   // rows 128..143 (need up to 127+KW-1 <= 131)
            gload_lds16(Ab + (long)(128 + srow) * CI + kk + scol,
                        As[buf] + 128 * 32);
#pragma unroll
        for (int dk = 0; dk < KW; dk++)
            gload_lds16(Bw + ((long)dk * CO + bcol + srow) * CI + kk + scol,
                        Bs[buf] + (dk * 64 + wid * 16) * 32);
    };

    STAGE(0, 0);
    const int fr = lane & 15, fk = (lane >> 4) * 8;
    int cur = 0;
    for (int kk = 0; kk < CI; kk += 32) {
        __syncthreads();                       // drains prev stage (vmcnt 0)
        if (kk + 32 < CI) STAGE(cur ^ 1, kk + 32);   // overlap with compute
        short8 bfr[KW][2];
#pragma unroll
        for (int dk = 0; dk < KW; dk++)
#pragma unroll
            for (int n = 0; n < 2; n++)
                bfr[dk][n] = *(const short8*)(Bs[cur] + (dk * 64 + wc * 32 + n * 16 + fr) * 32 + fk);
#pragma unroll
        for (int m = 0; m < 4; m++) {
#pragma unroll
            for (int dk = 0; dk < KW; dk++) {
                short8 af = *(const short8*)(As[cur] + (wr * 64 + m * 16 + fr + dk) * 32 + fk);
#pragma unroll
                for (int n = 0; n < 2; n++)
                    acc[m][n] = __builtin_amdgcn_mfma_f32_16x16x32_bf16(af, bfr[dk][n], acc[m][n], 0, 0, 0);
            }
        }
        cur ^= 1;
    }

    const int fq = (lane >> 4) * 4;
#pragma unroll
    for (int m = 0; m < 4; m++) {
#pragma unroll
        for (int n = 0; n < 2; n++) {
#pragma unroll
            for (int j = 0; j < 4; j++) {
                long row = brow + wr * 64 + m * 16 + fq + j;
                int col = (int)bcol + wc * 32 + n * 16 + fr;
                float v = acc[m][n][j] + bias[col];
                v = v / (1.f + __expf(-v));    // silu
                C[z * sCb + (crow_off + row) * ldc + col] = f2b(v);
            }
        }
    }
}

// ---------------------------------------------------------------------------
// Fused out-proj + gate GEMMs + residual epilogue:
//   X[row][col] += sigmoid(A2·B2 + b2) * (A1·B1 + b1)     (LAST: write OUT)
// 128x128 tile, dual accumulators, 2-phase double-buffered LDS (64 KiB).
// ---------------------------------------------------------------------------
template<int LAST>
__global__ __launch_bounds__(256)
void fused_og(const unsigned short* __restrict__ A1, const unsigned short* __restrict__ B1,
              const float* __restrict__ b1,
              const unsigned short* __restrict__ A2, const unsigned short* __restrict__ B2,
              const float* __restrict__ b2,
              float* __restrict__ X, float* __restrict__ OUT)
{
    __shared__ __align__(16) unsigned short S[2][4][128 * 32];
    const int tid = threadIdx.x, lane = tid & 63, wid = tid >> 6;
    const int wr = wid >> 1, wc = wid & 1;
    const long brow = (long)blockIdx.y * 128;
    const long bcol = (long)blockIdx.x * 128;
    const int srow = tid >> 2, scol = (tid & 3) * 8;

    const unsigned short* g0 = A1 + (brow + srow) * 1024 + scol;
    const unsigned short* g1 = B1 + (bcol + srow) * 1024 + scol;
    const unsigned short* g2 = A2 + (brow + srow) * 1024 + scol;
    const unsigned short* g3 = B2 + (bcol + srow) * 1024 + scol;

    f32x4 acc1[4][4] = {}, acc2[4][4] = {};

    auto STAGE = [&](int buf, int kk) {
#pragma unroll
        for (int o = 0; o < 2; o++) {
            gload_lds16(g0 + (long)o * 65536 + kk, S[buf][0] + (o * 64 + wid * 16) * 32);
            gload_lds16(g1 + (long)o * 65536 + kk, S[buf][1] + (o * 64 + wid * 16) * 32);
            gload_lds16(g2 + (long)o * 65536 + kk, S[buf][2] + (o * 64 + wid * 16) * 32);
            gload_lds16(g3 + (long)o * 65536 + kk, S[buf][3] + (o * 64 + wid * 16) * 32);
        }
    };

    STAGE(0, 0);
    const int fr = lane & 15, fk = (lane >> 4) * 8;
    int cur = 0;
    for (int kk = 0; kk < 1024; kk += 32) {
        __syncthreads();
        if (kk + 32 < 1024) STAGE(cur ^ 1, kk + 32);
        {
            short8 af[4], bf[4];
#pragma unroll
            for (int m = 0; m < 4; m++)
                af[m] = *(const short8*)(S[cur][0] + (wr * 64 + m * 16 + fr) * 32 + fk);
#pragma unroll
            for (int n = 0; n < 4; n++)
                bf[n] = *(const short8*)(S[cur][1] + (wc * 64 + n * 16 + fr) * 32 + fk);
#pragma unroll
            for (int m = 0; m < 4; m++)
#pragma unroll
                for (int n = 0; n < 4; n++)
                    acc1[m][n] = __builtin_amdgcn_mfma_f32_16x16x32_bf16(af[m], bf[n], acc1[m][n], 0, 0, 0);
        }
        {
            short8 af[4], bf[4];
#pragma unroll
            for (int m = 0; m < 4; m++)
                af[m] = *(const short8*)(S[cur][2] + (wr * 64 + m * 16 + fr) * 32 + fk);
#pragma unroll
            for (int n = 0; n < 4; n++)
                bf[n] = *(const short8*)(S[cur][3] + (wc * 64 + n * 16 + fr) * 32 + fk);
#pragma unroll
            for (int m = 0; m < 4; m++)
#pragma unroll
                for (int n = 0; n < 4; n++)
                    acc2[m][n] = __builtin_amdgcn_mfma_f32_16x16x32_bf16(af[m], bf[n], acc2[m][n], 0, 0, 0);
        }
        cur ^= 1;
    }

    const int fq = (lane >> 4) * 4;
#pragma unroll
    for (int m = 0; m < 4; m++) {
#pragma unroll
        for (int n = 0; n < 4; n++) {
#pragma unroll
            for (int j = 0; j < 4; j++) {
                long row = brow + wr * 64 + m * 16 + fq + j;
                int col = (int)bcol + wc * 64 + n * 16 + fr;
                float v1 = acc1[m][n][j] + b1[col];
                float v2 = acc2[m][n][j] + b2[col];
                long idx = row * 1024 + col;
                float r = X[idx] + v1 / (1.f + __expf(-v2));
                if (LAST) OUT[idx] = r; else X[idx] = r;
            }
        }
    }
}

// ---------------------------------------------------------------------------
// V transpose: VT[b][h][d][n] = V[b][n][h][d]
// ---------------------------------------------------------------------------
__global__ __launch_bounds__(256)
void vtrans_kernel(const unsigned short* __restrict__ qkv, unsigned short* __restrict__ vt)
{
    __shared__ unsigned short sm[64][72];
    const int nt = blockIdx.x, bh = blockIdx.y;
    const int b = bh >> 4, h = bh & 15;
    const int tid = threadIdx.x;
    const unsigned short* vsrc = qkv + ((long)b * 1024 + nt * 64) * 3072 + 2048 + h * 64;
    const int r = tid >> 2, c0 = (tid & 3) * 16;
#pragma unroll
    for (int t = 0; t < 2; t++) {
        short8 v = *(const short8*)(vsrc + (long)r * 3072 + c0 + t * 8);
        *(short8*)(&sm[r][c0 + t * 8]) = v;
    }
    __syncthreads();
    const int d = tid >> 2, n0 = (tid & 3) * 16;
    unsigned short tmp[16];
#pragma unroll
    for (int i = 0; i < 16; i++) tmp[i] = sm[n0 + i][d];
    unsigned short* dst = vt + ((long)bh * 64 + d) * 1024 + nt * 64 + n0;
    *(short8*)(dst) = *(const short8*)(tmp);
    *(short8*)(dst + 8) = *(const short8*)(tmp + 8);
}

// ---------------------------------------------------------------------------
// Flash attention, swapped-QK^T 32x32, no LDS in main loop (round-1 design).
// ---------------------------------------------------------------------------
__global__ __launch_bounds__(256)
void attn_kernel(const unsigned short* __restrict__ qkv,
                 const unsigned short* __restrict__ vt,
                 const float* __restrict__ plog,
                 unsigned short* __restrict__ y)
{
    __shared__ float pl[1024];
    const int qt = blockIdx.x;
    const int bh = blockIdx.y;
    const int b = bh >> 4, h = bh & 15;
    const int tid = threadIdx.x, lane = tid & 63, wid = tid >> 6;
    const int c = lane & 31;
    const int hh = lane >> 5;

    const long nb = (long)b * 1024;
    const unsigned short* qbase = qkv + nb * 3072 + h * 64;
    const unsigned short* kbase = qbase + 1024;
    const unsigned short* vtb = vt + (long)bh * 65536;

    for (int i = tid; i < 1024; i += 256) pl[i] = plog[b * 1024 + i];
    __syncthreads();

    const int q0 = qt * 128 + wid * 32;
    short8 qf[4];
#pragma unroll
    for (int d = 0; d < 4; d++)
        qf[d] = *(const short8*)(qbase + (long)(q0 + c) * 3072 + d * 16 + hh * 8);

    float m_run = -1e30f, l_run = 0.f;
    f32x16 o0 = {}, o1 = {};

    const unsigned short* kp = kbase + (long)c * 3072 + hh * 8;
    const unsigned short* vp = vtb + (long)c * 1024 + hh * 8;

    short8 kf[4], vf[4];
#pragma unroll
    for (int d = 0; d < 4; d++) kf[d] = *(const short8*)(kp + d * 16);
#pragma unroll
    for (int n2 = 0; n2 < 2; n2++)
#pragma unroll
        for (int kh = 0; kh < 2; kh++)
            vf[n2 * 2 + kh] = *(const short8*)(vp + n2 * 32768 + kh * 16);

    for (int kt = 0; kt < 1024; kt += 32) {
        f32x16 s = {};
#pragma unroll
        for (int d = 0; d < 4; d++)
            s = __builtin_amdgcn_mfma_f32_32x32x16_bf16(kf[d], qf[d], s, 0, 0, 0);

        short8 kn[4], vn[4];
        const bool more = (kt + 32) < 1024;
        if (more) {
#pragma unroll
            for (int d = 0; d < 4; d++)
                kn[d] = *(const short8*)(kp + (long)(kt + 32) * 3072 + d * 16);
#pragma unroll
            for (int n2 = 0; n2 < 2; n2++)
#pragma unroll
                for (int kh = 0; kh < 2; kh++)
                    vn[n2 * 2 + kh] = *(const short8*)(vp + n2 * 32768 + (kt + 32) + kh * 16);
        }

        float mx = -1e30f;
#pragma unroll
        for (int r = 0; r < 16; r++) {
            int key = (r & 3) + 8 * (r >> 2) + 4 * hh;
            float pv = s[r] * 0.125f + pl[kt + key];
            s[r] = pv;
            mx = fmaxf(mx, pv);
        }
        mx = fmaxf(mx, __shfl_xor(mx, 32));

        if (!__all(mx - m_run <= 8.f)) {
            float mnew = fmaxf(m_run, mx);
            float f = __expf(m_run - mnew);
            l_run *= f;
#pragma unroll
            for (int r = 0; r < 16; r++) {
                int qrow = (r & 3) + 8 * (r >> 2) + 4 * hh;
                float fr2 = __shfl(f, qrow);
                o0[r] *= fr2;
                o1[r] *= fr2;
            }
            m_run = mnew;
        }

        float sum = 0.f;
        unsigned int pk[8];
#pragma unroll
        for (int bb = 0; bb < 4; bb++) {
#pragma unroll
            for (int t = 0; t < 2; t++) {
                float e0 = __expf(s[bb * 4 + 2 * t] - m_run);
                float e1 = __expf(s[bb * 4 + 2 * t + 1] - m_run);
                sum += e0 + e1;
                pk[bb * 2 + t] = (unsigned int)f2b(e0) | ((unsigned int)f2b(e1) << 16);
            }
        }
        sum += __shfl_xor(sum, 32);
        l_run += sum;

        unsigned int sx0 = (unsigned int)__shfl_xor((int)pk[0], 32);
        unsigned int sx1 = (unsigned int)__shfl_xor((int)pk[1], 32);
        unsigned int sx2 = (unsigned int)__shfl_xor((int)pk[2], 32);
        unsigned int sx3 = (unsigned int)__shfl_xor((int)pk[3], 32);
        unsigned int sx4 = (unsigned int)__shfl_xor((int)pk[4], 32);
        unsigned int sx5 = (unsigned int)__shfl_xor((int)pk[5], 32);
        unsigned int sx6 = (unsigned int)__shfl_xor((int)pk[6], 32);
        unsigned int sx7 = (unsigned int)__shfl_xor((int)pk[7], 32);
        union U8 { unsigned int u[4]; short8 v; } A0, A1;
        A0.u[0] = hh ? sx2 : pk[0];
        A0.u[1] = hh ? sx3 : pk[1];
        A0.u[2] = hh ? pk[2] : sx0;
        A0.u[3] = hh ? pk[3] : sx1;
        A1.u[0] = hh ? sx6 : pk[4];
        A1.u[1] = hh ? sx7 : pk[5];
        A1.u[2] = hh ? pk[6] : sx4;
        A1.u[3] = hh ? pk[7] : sx5;

        o0 = __builtin_amdgcn_mfma_f32_32x32x16_bf16(A0.v, vf[0], o0, 0, 0, 0);
        o0 = __builtin_amdgcn_mfma_f32_32x32x16_bf16(A1.v, vf[1], o0, 0, 0, 0);
        o1 = __builtin_amdgcn_mfma_f32_32x32x16_bf16(A0.v, vf[2], o1, 0, 0, 0);
        o1 = __builtin_amdgcn_mfma_f32_32x32x16_bf16(A1.v, vf[3], o1, 0, 0, 0);

        if (more) {
#pragma unroll
            for (int d = 0; d < 4; d++) kf[d] = kn[d];
#pragma unroll
            for (int i = 0; i < 4; i++) vf[i] = vn[i];
        }
    }

#pragma unroll
    for (int r = 0; r < 16; r++) {
        int qrow = (r & 3) + 8 * (r >> 2) + 4 * hh;
        float lr = __shfl(l_run, qrow);
        float inv = 1.f / lr;
        long row = nb + q0 + qrow;
        y[row * 1024 + h * 64 + c] = f2b(o0[r] * inv);
        y[row * 1024 + h * 64 + 32 + c] = f2b(o1[r] * inv);
    }
}

// --------------------------------------------------------------------------
__global__ __launch_bounds__(256)
void zcrms_kernel(const float* __restrict__ x, const float* __restrict__ g,
                  unsigned short* __restrict__ hn)
{
    __shared__ float red[8];
    const long row = blockIdx.x;
    const int tid = threadIdx.x;
    const float* xr = x + row * 1024;
    float4 v = *(const float4*)(xr + tid * 4);
    float s = v.x + v.y + v.z + v.w;
#pragma unroll
    for (int m = 32; m; m >>= 1) s += __shfl_xor(s, m);
    const int lane = tid & 63, wid = tid >> 6;
    if (lane == 0) red[wid] = s;
    __syncthreads();
    float mean = (red[0] + red[1] + red[2] + red[3]) * (1.f / 1024.f);
    float c0 = v.x - mean, c1 = v.y - mean, c2 = v.z - mean, c3 = v.w - mean;
    float s2 = c0 * c0 + c1 * c1 + c2 * c2 + c3 * c3;
#pragma unroll
    for (int m = 32; m; m >>= 1) s2 += __shfl_xor(s2, m);
    if (lane == 0) red[4 + wid] = s2;
    __syncthreads();
    float rinv = rsqrtf((red[4] + red[5] + red[6] + red[7]) * (1.f / 1024.f) + 1e-8f);
    const float* gr = g + tid * 4;
    unsigned int lo = (unsigned int)f2b(c0 * rinv * gr[0]) | ((unsigned int)f2b(c1 * rinv * gr[1]) << 16);
    unsigned int hi = (unsigned int)f2b(c2 * rinv * gr[2]) | ((unsigned int)f2b(c3 * rinv * gr[3]) << 16);
    uint2 u; u.x = lo; u.y = hi;
    *(uint2*)(hn + row * 1024 + tid * 4) = u;
}

__global__ __launch_bounds__(1024)
void embed_kernel(const float* __restrict__ patches, const float* __restrict__ W,
                  const float* __restrict__ bias, float* __restrict__ x,
                  unsigned short* __restrict__ xpad)
{
    __shared__ float sp[8][75];
    const long r0 = (long)blockIdx.x * 8;
    const int tid = threadIdx.x;
    for (int i = tid; i < 600; i += 1024) sp[i / 75][i % 75] = patches[r0 * 75 + i];
    __syncthreads();
    float acc[8];
    float bb = bias[tid];
#pragma unroll
    for (int j = 0; j < 8; j++) acc[j] = bb;
    for (int p = 0; p < 75; p++) {
        float w = W[p * 1024 + tid];
#pragma unroll
        for (int j = 0; j < 8; j++) acc[j] += sp[j][p] * w;
    }
#pragma unroll
    for (int j = 0; j < 8; j++) {
        long r = r0 + j;
        x[r * 1024 + tid] = acc[j];
        long bb2 = r >> 10, n = r & 1023;
        xpad[(bb2 * 1028 + n + 2) * 1024 + tid] = f2b(acc[j]);
    }
}

__global__ void rope_table_kernel(float* __restrict__ tab)
{
    int idx = blockIdx.x * 256 + threadIdx.x;   // 32768
    int n = idx >> 5, i = idx & 31;
    float inv = powf(10000.0f, -(float)i * (1.0f / 32.0f));
    float ang = (float)n * inv;
    tab[idx] = cosf(ang);
    tab[32768 + idx] = sinf(ang);
}

__global__ __launch_bounds__(256)
void conv3_kernel(const unsigned short* __restrict__ h2, const float* __restrict__ w3,
                  const float* __restrict__ b3, float* __restrict__ logits)
{
    const long row = (long)blockIdx.x * 4 + (threadIdx.x >> 6);
    const int lane = threadIdx.x & 63;
    const unsigned short* hr = h2 + row * 256;
    float s = 0.f;
#pragma unroll
    for (int t = 0; t < 4; t++) s += b2f(hr[lane + t * 64]) * w3[lane + t * 64];
#pragma unroll
    for (int m = 32; m; m >>= 1) s += __shfl_xor(s, m);
    if (lane == 0) logits[row] = s + b3[0];
}

__global__ __launch_bounds__(256)
void winmax_kernel(const float* __restrict__ logits, float* __restrict__ win)
{
    __shared__ float red[4];
    const int b = blockIdx.x, tid = threadIdx.x;
    float m = -1e30f;
    for (int i = tid; i < 1024; i += 256) m = fmaxf(m, logits[b * 1024 + i]);
#pragma unroll
    for (int k = 32; k; k >>= 1) m = fmaxf(m, __shfl_xor(m, k));
    if ((tid & 63) == 0) red[tid >> 6] = m;
    __syncthreads();
    if (tid == 0) win[b] = fmaxf(fmaxf(red[0], red[1]), fmaxf(red[2], red[3]));
}

// f32 (K,Nc) -> bf16 (Nc,K), batched over z
__global__ __launch_bounds__(256)
void wtrans_kernel(const float* __restrict__ in, unsigned short* __restrict__ out,
                   int K, int Nc)
{
    __shared__ float tile[32][33];
    const long base = (long)blockIdx.z * K * Nc;
    const int k0 = blockIdx.y * 32, n0 = blockIdx.x * 32;
    const int tx = threadIdx.x & 31, ty = threadIdx.x >> 5;
#pragma unroll
    for (int r = ty; r < 32; r += 8) tile[r][tx] = in[base + (long)(k0 + r) * Nc + n0 + tx];
    __syncthreads();
#pragma unroll
    for (int r = ty; r < 32; r += 8) out[base + (long)(n0 + r) * K + k0 + tx] = f2b(tile[tx][r]);
}

// (Co,Ci,Kw) f32 -> [dk][co][ci] bf16
__global__ void wconv_tap_kernel(const float* __restrict__ in, unsigned short* __restrict__ out,
                                 int CI, int KW, int CO, long total)
{
    long idx = (long)blockIdx.x * 256 + threadIdx.x;
    if (idx >= total) return;
    int ci = (int)(idx % CI);
    long t = idx / CI;
    int co = (int)(t % CO);
    int dk = (int)(t / CO);
    out[idx] = f2b(in[((long)co * CI + ci) * KW + dk]);
}

// ---------------------------------------------------------------------------
extern "C" void kernel_launch(void* const* d_in, const int* in_sizes, int n_in,
                              void* d_out, int out_size, void* d_ws, size_t ws_size,
                              hipStream_t stream)
{
    (void)in_sizes; (void)n_in; (void)out_size; (void)ws_size;
    const float* patches = (const float*)d_in[0];
    const float* embed_w = (const float*)d_in[1];
    const float* embed_b = (const float*)d_in[2];
    const float* bd_w1 = (const float*)d_in[3];
    const float* bd_b1 = (const float*)d_in[4];
    const float* bd_w2 = (const float*)d_in[5];
    const float* bd_b2 = (const float*)d_in[6];
    const float* bd_w3 = (const float*)d_in[7];
    const float* bd_b3 = (const float*)d_in[8];
    const float* norm_g = (const float*)d_in[9];
    const float* qkv_w = (const float*)d_in[10];
    const float* qkv_b = (const float*)d_in[11];
    const float* out_w = (const float*)d_in[12];
    const float* out_b = (const float*)d_in[13];
    const float* gate_w = (const float*)d_in[14];
    const float* gate_b = (const float*)d_in[15];

    char* p = (char*)d_ws;
    auto alloc = [&](size_t bytes) { char* r = p; p += (bytes + 255) & ~(size_t)255; return r; };
    unsigned short* WQ   = (unsigned short*)alloc(3ll * 3072 * 1024 * 2);
    unsigned short* WO   = (unsigned short*)alloc(3ll * 1024 * 1024 * 2);
    unsigned short* WG   = (unsigned short*)alloc(3ll * 1024 * 1024 * 2);
    unsigned short* W1S  = (unsigned short*)alloc(5ll * 512 * 1024 * 2);
    unsigned short* W2S  = (unsigned short*)alloc(3ll * 256 * 512 * 2);
    unsigned short* XPAD = (unsigned short*)alloc(4ll * 1028 * 1024 * 2);
    unsigned short* H1P  = (unsigned short*)alloc(4ll * 1026 * 512 * 2);
    unsigned short* H2   = (unsigned short*)alloc(4ll * 1024 * 256 * 2);
    float*          X    = (float*)alloc(4ll * 1024 * 1024 * 4);
    unsigned short* HN   = (unsigned short*)alloc(4096ll * 1024 * 2);
    unsigned short* QKV  = (unsigned short*)alloc(4096ll * 3072 * 2);
    unsigned short* YATT = (unsigned short*)alloc(4096ll * 1024 * 2);
    float*          LOGI = (float*)alloc(4096 * 4);
    float*          ROPE = (float*)alloc(65536 * 4);
    // VT (B,H,64,1024) bf16 = 8MB aliased onto XPAD (conv pipeline done first)
    unsigned short* VT   = XPAD;

    hipMemsetAsync(XPAD, 0, 4ll * 1028 * 1024 * 2, stream);
    hipMemsetAsync(H1P, 0, 4ll * 1026 * 512 * 2, stream);

    wtrans_kernel<<<dim3(96, 32, 3), 256, 0, stream>>>(qkv_w, WQ, 1024, 3072);
    wtrans_kernel<<<dim3(32, 32, 3), 256, 0, stream>>>(out_w, WO, 1024, 1024);
    wtrans_kernel<<<dim3(32, 32, 3), 256, 0, stream>>>(gate_w, WG, 1024, 1024);
    wconv_tap_kernel<<<10240, 256, 0, stream>>>(bd_w1, W1S, 1024, 5, 512, 5ll * 512 * 1024);
    wconv_tap_kernel<<<1536, 256, 0, stream>>>(bd_w2, W2S, 512, 3, 256, 3ll * 256 * 512);
    rope_table_kernel<<<128, 256, 0, stream>>>(ROPE);
    embed_kernel<<<512, 1024, 0, stream>>>(patches, embed_w, embed_b, X, XPAD);

    // conv1: 128 rows x 64 out-ch tiles, taps in-kernel
    conv_gemm<5, 1024><<<dim3(8, 8, 4), 256, 0, stream>>>(XPAD, 1028ll * 1024, W1S, 512, bd_b1,
                                                          H1P, 1026ll * 512, 512, 1);
    conv_gemm<3, 512><<<dim3(4, 8, 4), 256, 0, stream>>>(H1P, 1026ll * 512, W2S, 256, bd_b2,
                                                         H2, 1024ll * 256, 256, 0);
    conv3_kernel<<<1024, 256, 0, stream>>>(H2, bd_w3, bd_b3, LOGI);
    winmax_kernel<<<4, 256, 0, stream>>>(LOGI, (float*)d_out + 4194304);

    for (int l = 0; l < 3; l++) {
        zcrms_kernel<<<4096, 256, 0, stream>>>(X, norm_g + l * 1024, HN);
        qkv_gemm<<<dim3(24, 32), 256, 0, stream>>>(HN, WQ + (long)l * 3072 * 1024,
                                                   qkv_b + l * 3072, QKV, ROPE);
        vtrans_kernel<<<dim3(16, 64), 256, 0, stream>>>(QKV, VT);
        attn_kernel<<<dim3(8, 64), 256, 0, stream>>>(QKV, VT, LOGI, YATT);
        if (l < 2)
            fused_og<0><<<dim3(8, 32), 256, 0, stream>>>(YATT, WO + (long)l * 1024 * 1024, out_b + l * 1024,
                                                         HN, WG + (long)l * 1024 * 1024, gate_b + l * 1024,
                                                         X, nullptr);
        else
            fused_og<1><<<dim3(8, 32), 256, 0, stream>>>(YATT, WO + (long)l * 1024 * 1024, out_b + l * 1024,
                                                         HN, WG + (long)l * 1024 * 1024, gate_b + l * 1024,
                                                         X, (float*)d_out);
    }
}

// Round 4
// 554.391 us; speedup vs baseline: 1.7605x; 1.0921x over previous
//
#include <hip/hip_runtime.h>
#include <stdint.h>
#include <math.h>

typedef __attribute__((ext_vector_type(8))) short short8;
typedef __attribute__((ext_vector_type(4))) float f32x4;
typedef __attribute__((ext_vector_type(16))) float f32x16;

__device__ __forceinline__ float b2f(unsigned short u) {
    union { unsigned int i; float f; } v; v.i = ((unsigned int)u) << 16; return v.f;
}
__device__ __forceinline__ unsigned short f2b(float f) {
    union { float f; unsigned int i; } v; v.f = f;
    unsigned int r = v.i + 0x7fffu + ((v.i >> 16) & 1u);
    return (unsigned short)(r >> 16);
}

__device__ __forceinline__ void gload_lds16(const void* g, void* l) {
    __builtin_amdgcn_global_load_lds((__attribute__((address_space(1))) void*)g,
                                     (__attribute__((address_space(3))) void*)l,
                                     16, 0, 0);
}

// ---------------------------------------------------------------------------
// qkv GEMM with fused RoPE epilogue.
// ---------------------------------------------------------------------------
__global__ __launch_bounds__(256)
void qkv_gemm(const unsigned short* __restrict__ A,
              const unsigned short* __restrict__ Bw,
              const float* __restrict__ bias,
              unsigned short* __restrict__ Cb,
              const float* __restrict__ rope)
{
    __shared__ __align__(16) unsigned short As[128 * 32];
    __shared__ __align__(16) unsigned short Bs[128 * 32];
    const int tid = threadIdx.x;
    const int lane = tid & 63, wid = tid >> 6;
    const int wr = wid >> 1, wc = wid & 1;
    const long brow = (long)blockIdx.y * 128;
    const long bcol = (long)blockIdx.x * 128;

    const int arow = tid >> 2;
    const int acol = (tid & 3) * 8;
    const unsigned short* ga0 = A + (brow + arow) * 1024 + acol;
    const unsigned short* ga1 = A + (brow + 64 + arow) * 1024 + acol;
    const unsigned short* gb0 = Bw + (bcol + arow) * 1024 + acol;
    const unsigned short* gb1 = Bw + (bcol + 64 + arow) * 1024 + acol;
    unsigned short* la0 = As + wid * 512;
    unsigned short* la1 = As + 2048 + wid * 512;
    unsigned short* lb0 = Bs + wid * 512;
    unsigned short* lb1 = Bs + 2048 + wid * 512;

    f32x4 acc[4][4] = {};

    for (int kk = 0; kk < 1024; kk += 32) {
        gload_lds16(ga0 + kk, la0);
        gload_lds16(ga1 + kk, la1);
        gload_lds16(gb0 + kk, lb0);
        gload_lds16(gb1 + kk, lb1);
        __syncthreads();
        const int fr = lane & 15, fk = (lane >> 4) * 8;
        short8 af[4], bfrag[4];
#pragma unroll
        for (int m = 0; m < 4; m++)
            af[m] = *(const short8*)(As + (wr * 64 + m * 16 + fr) * 32 + fk);
#pragma unroll
        for (int n = 0; n < 4; n++)
            bfrag[n] = *(const short8*)(Bs + (wc * 64 + n * 16 + fr) * 32 + fk);
#pragma unroll
        for (int m = 0; m < 4; m++)
#pragma unroll
            for (int n = 0; n < 4; n++)
                acc[m][n] = __builtin_amdgcn_mfma_f32_16x16x32_bf16(af[m], bfrag[n], acc[m][n], 0, 0, 0);
        __syncthreads();
    }

    const int fr = lane & 15;
    const int fq = (lane >> 4) * 4;
#pragma unroll
    for (int m = 0; m < 4; m++) {
#pragma unroll
        for (int n = 0; n < 4; n++) {
#pragma unroll
            for (int j = 0; j < 4; j++) {
                long row = brow + wr * 64 + m * 16 + fq + j;
                int col = (int)bcol + wc * 64 + n * 16 + fr;
                float v = acc[m][n][j] + bias[col];
                float part = __shfl_xor(v, 1);   // partner col (d^1), same row
                if (col < 2048) {
                    int d = col & 63;
                    int i2 = d >> 1;
                    int ntok = (int)(row & 1023);
                    float cc = rope[ntok * 32 + i2];
                    float ss = rope[32768 + ntok * 32 + i2];
                    v = (d & 1) ? (part * ss + v * cc) : (v * cc - part * ss);
                }
                Cb[row * 3072 + col] = f2b(v);
            }
        }
    }
}

// ---------------------------------------------------------------------------
// Tap-accumulation conv-as-GEMM (unchanged from round 2).
// ---------------------------------------------------------------------------
template<int KW, int CI>
__global__ __launch_bounds__(256)
void conv_gemm(const unsigned short* __restrict__ A, long sAb,
               const unsigned short* __restrict__ Bw, int CO,
               const float* __restrict__ bias,
               unsigned short* __restrict__ C, long sCb, int ldc, int crow_off)
{
    __shared__ __align__(16) unsigned short As[2][144 * 32];
    __shared__ __align__(16) unsigned short Bs[2][KW * 64 * 32];
    const int tid = threadIdx.x, lane = tid & 63, wid = tid >> 6;
    const int wr = wid >> 1, wc = wid & 1;
    const int z = blockIdx.z;
    const long brow = (long)blockIdx.y * 128;
    const long bcol = (long)blockIdx.x * 64;
    const unsigned short* Ab = A + z * sAb + brow * CI;
    const int srow = tid >> 2, scol = (tid & 3) * 8;

    f32x4 acc[4][2] = {};

    auto STAGE = [&](int buf, int kk) {
#pragma unroll
        for (int o = 0; o < 2; o++)
            gload_lds16(Ab + (long)(o * 64 + srow) * CI + kk + scol,
                        As[buf] + (o * 64 + wid * 16) * 32);
        if (wid == 0)
            gload_lds16(Ab + (long)(128 + srow) * CI + kk + scol,
                        As[buf] + 128 * 32);
#pragma unroll
        for (int dk = 0; dk < KW; dk++)
            gload_lds16(Bw + ((long)dk * CO + bcol + srow) * CI + kk + scol,
                        Bs[buf] + (dk * 64 + wid * 16) * 32);
    };

    STAGE(0, 0);
    const int fr = lane & 15, fk = (lane >> 4) * 8;
    int cur = 0;
    for (int kk = 0; kk < CI; kk += 32) {
        __syncthreads();
        if (kk + 32 < CI) STAGE(cur ^ 1, kk + 32);
        short8 bfr[KW][2];
#pragma unroll
        for (int dk = 0; dk < KW; dk++)
#pragma unroll
            for (int n = 0; n < 2; n++)
                bfr[dk][n] = *(const short8*)(Bs[cur] + (dk * 64 + wc * 32 + n * 16 + fr) * 32 + fk);
#pragma unroll
        for (int m = 0; m < 4; m++) {
#pragma unroll
            for (int dk = 0; dk < KW; dk++) {
                short8 af = *(const short8*)(As[cur] + (wr * 64 + m * 16 + fr + dk) * 32 + fk);
#pragma unroll
                for (int n = 0; n < 2; n++)
                    acc[m][n] = __builtin_amdgcn_mfma_f32_16x16x32_bf16(af, bfr[dk][n], acc[m][n], 0, 0, 0);
            }
        }
        cur ^= 1;
    }

    const int fq = (lane >> 4) * 4;
#pragma unroll
    for (int m = 0; m < 4; m++) {
#pragma unroll
        for (int n = 0; n < 2; n++) {
#pragma unroll
            for (int j = 0; j < 4; j++) {
                long row = brow + wr * 64 + m * 16 + fq + j;
                int col = (int)bcol + wc * 32 + n * 16 + fr;
                float v = acc[m][n][j] + bias[col];
                v = v / (1.f + __expf(-v));    // silu
                C[z * sCb + (crow_off + row) * ldc + col] = f2b(v);
            }
        }
    }
}

// ---------------------------------------------------------------------------
// Fused out-proj + gate GEMMs + residual epilogue (unchanged from round 2).
// ---------------------------------------------------------------------------
template<int LAST>
__global__ __launch_bounds__(256)
void fused_og(const unsigned short* __restrict__ A1, const unsigned short* __restrict__ B1,
              const float* __restrict__ b1,
              const unsigned short* __restrict__ A2, const unsigned short* __restrict__ B2,
              const float* __restrict__ b2,
              float* __restrict__ X, float* __restrict__ OUT)
{
    __shared__ __align__(16) unsigned short S[2][4][128 * 32];
    const int tid = threadIdx.x, lane = tid & 63, wid = tid >> 6;
    const int wr = wid >> 1, wc = wid & 1;
    const long brow = (long)blockIdx.y * 128;
    const long bcol = (long)blockIdx.x * 128;
    const int srow = tid >> 2, scol = (tid & 3) * 8;

    const unsigned short* g0 = A1 + (brow + srow) * 1024 + scol;
    const unsigned short* g1 = B1 + (bcol + srow) * 1024 + scol;
    const unsigned short* g2 = A2 + (brow + srow) * 1024 + scol;
    const unsigned short* g3 = B2 + (bcol + srow) * 1024 + scol;

    f32x4 acc1[4][4] = {}, acc2[4][4] = {};

    auto STAGE = [&](int buf, int kk) {
#pragma unroll
        for (int o = 0; o < 2; o++) {
            gload_lds16(g0 + (long)o * 65536 + kk, S[buf][0] + (o * 64 + wid * 16) * 32);
            gload_lds16(g1 + (long)o * 65536 + kk, S[buf][1] + (o * 64 + wid * 16) * 32);
            gload_lds16(g2 + (long)o * 65536 + kk, S[buf][2] + (o * 64 + wid * 16) * 32);
            gload_lds16(g3 + (long)o * 65536 + kk, S[buf][3] + (o * 64 + wid * 16) * 32);
        }
    };

    STAGE(0, 0);
    const int fr = lane & 15, fk = (lane >> 4) * 8;
    int cur = 0;
    for (int kk = 0; kk < 1024; kk += 32) {
        __syncthreads();
        if (kk + 32 < 1024) STAGE(cur ^ 1, kk + 32);
        {
            short8 af[4], bf[4];
#pragma unroll
            for (int m = 0; m < 4; m++)
                af[m] = *(const short8*)(S[cur][0] + (wr * 64 + m * 16 + fr) * 32 + fk);
#pragma unroll
            for (int n = 0; n < 4; n++)
                bf[n] = *(const short8*)(S[cur][1] + (wc * 64 + n * 16 + fr) * 32 + fk);
#pragma unroll
            for (int m = 0; m < 4; m++)
#pragma unroll
                for (int n = 0; n < 4; n++)
                    acc1[m][n] = __builtin_amdgcn_mfma_f32_16x16x32_bf16(af[m], bf[n], acc1[m][n], 0, 0, 0);
        }
        {
            short8 af[4], bf[4];
#pragma unroll
            for (int m = 0; m < 4; m++)
                af[m] = *(const short8*)(S[cur][2] + (wr * 64 + m * 16 + fr) * 32 + fk);
#pragma unroll
            for (int n = 0; n < 4; n++)
                bf[n] = *(const short8*)(S[cur][3] + (wc * 64 + n * 16 + fr) * 32 + fk);
#pragma unroll
            for (int m = 0; m < 4; m++)
#pragma unroll
                for (int n = 0; n < 4; n++)
                    acc2[m][n] = __builtin_amdgcn_mfma_f32_16x16x32_bf16(af[m], bf[n], acc2[m][n], 0, 0, 0);
        }
        cur ^= 1;
    }

    const int fq = (lane >> 4) * 4;
#pragma unroll
    for (int m = 0; m < 4; m++) {
#pragma unroll
        for (int n = 0; n < 4; n++) {
#pragma unroll
            for (int j = 0; j < 4; j++) {
                long row = brow + wr * 64 + m * 16 + fq + j;
                int col = (int)bcol + wc * 64 + n * 16 + fr;
                float v1 = acc1[m][n][j] + b1[col];
                float v2 = acc2[m][n][j] + b2[col];
                long idx = row * 1024 + col;
                float r = X[idx] + v1 / (1.f + __expf(-v2));
                if (LAST) OUT[idx] = r; else X[idx] = r;
            }
        }
    }
}

// ---------------------------------------------------------------------------
// V transpose: VT[b][h][d][n] = V[b][n][h][d]
// ---------------------------------------------------------------------------
__global__ __launch_bounds__(256)
void vtrans_kernel(const unsigned short* __restrict__ qkv, unsigned short* __restrict__ vt)
{
    __shared__ unsigned short sm[64][72];
    const int nt = blockIdx.x, bh = blockIdx.y;
    const int b = bh >> 4, h = bh & 15;
    const int tid = threadIdx.x;
    const unsigned short* vsrc = qkv + ((long)b * 1024 + nt * 64) * 3072 + 2048 + h * 64;
    const int r = tid >> 2, c0 = (tid & 3) * 16;
#pragma unroll
    for (int t = 0; t < 2; t++) {
        short8 v = *(const short8*)(vsrc + (long)r * 3072 + c0 + t * 8);
        *(short8*)(&sm[r][c0 + t * 8]) = v;
    }
    __syncthreads();
    const int d = tid >> 2, n0 = (tid & 3) * 16;
    unsigned short tmp[16];
#pragma unroll
    for (int i = 0; i < 16; i++) tmp[i] = sm[n0 + i][d];
    unsigned short* dst = vt + ((long)bh * 64 + d) * 1024 + nt * 64 + n0;
    *(short8*)(dst) = *(const short8*)(tmp);
    *(short8*)(dst + 8) = *(const short8*)(tmp + 8);
}

// ---------------------------------------------------------------------------
// Flash attention v3: swapped-QK^T 32x32 + LDS-staged K/V tiles.
// grid (64 bh, 8 qt) -> linear id ≡ bh (mod 8): all q-tiles of a head on one
// XCD (K/V L2-resident, fetched once). Per 32-key tile: K (32x64, 128B rows)
// and VT (64x32, 64B rows) staged ONCE per block via global_load_lds with
// PRE-SWIZZLED global source (LDS linear; chunk16 j stored at j^(r&7) for K,
// j^((d>>1)&3) for V) so ds_read_b128 fragment reads are at the bank floor.
// Double-buffered, one __syncthreads per tile (drains own vmcnt + barrier).
// ---------------------------------------------------------------------------
__global__ __launch_bounds__(256)
void attn_kernel(const unsigned short* __restrict__ qkv,
                 const unsigned short* __restrict__ vt,
                 const float* __restrict__ plog,
                 unsigned short* __restrict__ y)
{
    __shared__ __align__(16) unsigned short Kb[2][32 * 64];
    __shared__ __align__(16) unsigned short Vb[2][64 * 32];
    __shared__ float pl[1024];

    const int bh = blockIdx.x;          // bh major: XCD locality
    const int qt = blockIdx.y;
    const int b = bh >> 4, h = bh & 15;
    const int tid = threadIdx.x, lane = tid & 63, wid = tid >> 6;
    const int c = lane & 31;
    const int hh = lane >> 5;

    const long nb = (long)b * 1024;
    const unsigned short* qbase = qkv + nb * 3072 + h * 64;
    const unsigned short* kbase = qbase + 1024;
    const unsigned short* vtb = vt + (long)bh * 65536;

    for (int i = tid; i < 1024; i += 256) pl[i] = plog[b * 1024 + i];

    // staging geometry (per 256-thread block, 1 inst per buffer per thread)
    const int krow = (tid >> 3) & 31;                  // wid*8 + (lane>>3)
    const int kchk = (lane & 7) ^ ((lane >> 3) & 7);   // pre-swizzled source chunk
    const unsigned short* gk = kbase + (long)krow * 3072 + kchk * 8;
    unsigned short* lk = Kb[0] + wid * 512;            // +buf offset applied below

    const int vrow = (tid >> 2) & 63;                  // wid*16 + (lane>>2)
    const int vchk = (lane & 3) ^ ((lane >> 3) & 3);
    const unsigned short* gv = vtb + (long)vrow * 1024 + vchk * 8;
    unsigned short* lv = Vb[0] + wid * 512;

    auto STAGE = [&](int buf, int kt) {
        gload_lds16(gk + (long)kt * 3072, lk + buf * 2048);
        gload_lds16(gv + kt, lv + buf * 2048);
    };

    const int q0 = qt * 128 + wid * 32;
    short8 qf[4];
#pragma unroll
    for (int d = 0; d < 4; d++)
        qf[d] = *(const short8*)(qbase + (long)(q0 + c) * 3072 + d * 16 + hh * 8);

    float m_run = -1e30f, l_run = 0.f;
    f32x16 o0 = {}, o1 = {};

    STAGE(0, 0);
    int cur = 0;
    for (int kt = 0; kt < 1024; kt += 32) {
        __syncthreads();                       // tile[cur] ready; prev reads done
        if (kt + 32 < 1024) STAGE(cur ^ 1, kt + 32);

        // K fragments from LDS (swizzled chunk addressing, bank-floor)
        short8 kf[4];
#pragma unroll
        for (int d = 0; d < 4; d++)
            kf[d] = *(const short8*)(Kb[cur] + c * 64 + (((2 * d + hh) ^ (c & 7)) * 8));

        f32x16 s = {};
#pragma unroll
        for (int d = 0; d < 4; d++)
            s = __builtin_amdgcn_mfma_f32_32x32x16_bf16(kf[d], qf[d], s, 0, 0, 0);

        float mx = -1e30f;
#pragma unroll
        for (int r = 0; r < 16; r++) {
            int key = (r & 3) + 8 * (r >> 2) + 4 * hh;
            float pv = s[r] * 0.125f + pl[kt + key];
            s[r] = pv;
            mx = fmaxf(mx, pv);
        }
        mx = fmaxf(mx, __shfl_xor(mx, 32));

        if (!__all(mx - m_run <= 8.f)) {       // defer-max (T13)
            float mnew = fmaxf(m_run, mx);
            float f = __expf(m_run - mnew);
            l_run *= f;
#pragma unroll
            for (int r = 0; r < 16; r++) {
                int qrow = (r & 3) + 8 * (r >> 2) + 4 * hh;
                float fr2 = __shfl(f, qrow);
                o0[r] *= fr2;
                o1[r] *= fr2;
            }
            m_run = mnew;
        }

        float sum = 0.f;
        unsigned int pk[8];
#pragma unroll
        for (int bb = 0; bb < 4; bb++) {
#pragma unroll
            for (int t = 0; t < 2; t++) {
                float e0 = __expf(s[bb * 4 + 2 * t] - m_run);
                float e1 = __expf(s[bb * 4 + 2 * t + 1] - m_run);
                sum += e0 + e1;
                pk[bb * 2 + t] = (unsigned int)f2b(e0) | ((unsigned int)f2b(e1) << 16);
            }
        }
        sum += __shfl_xor(sum, 32);
        l_run += sum;

        unsigned int sx0 = (unsigned int)__shfl_xor((int)pk[0], 32);
        unsigned int sx1 = (unsigned int)__shfl_xor((int)pk[1], 32);
        unsigned int sx2 = (unsigned int)__shfl_xor((int)pk[2], 32);
        unsigned int sx3 = (unsigned int)__shfl_xor((int)pk[3], 32);
        unsigned int sx4 = (unsigned int)__shfl_xor((int)pk[4], 32);
        unsigned int sx5 = (unsigned int)__shfl_xor((int)pk[5], 32);
        unsigned int sx6 = (unsigned int)__shfl_xor((int)pk[6], 32);
        unsigned int sx7 = (unsigned int)__shfl_xor((int)pk[7], 32);
        union U8 { unsigned int u[4]; short8 v; } A0, A1;
        A0.u[0] = hh ? sx2 : pk[0];
        A0.u[1] = hh ? sx3 : pk[1];
        A0.u[2] = hh ? pk[2] : sx0;
        A0.u[3] = hh ? pk[3] : sx1;
        A1.u[0] = hh ? sx6 : pk[4];
        A1.u[1] = hh ? sx7 : pk[5];
        A1.u[2] = hh ? pk[6] : sx4;
        A1.u[3] = hh ? pk[7] : sx5;

        // V fragments from LDS: rows c (o0) and c+32 (o1), chunk (2*sub+hh)
        const int vsw = (c >> 1) & 3;
        short8 vf00 = *(const short8*)(Vb[cur] + c * 32 + ((hh ^ vsw) * 8));
        short8 vf01 = *(const short8*)(Vb[cur] + c * 32 + (((2 + hh) ^ vsw) * 8));
        short8 vf10 = *(const short8*)(Vb[cur] + (c + 32) * 32 + ((hh ^ vsw) * 8));
        short8 vf11 = *(const short8*)(Vb[cur] + (c + 32) * 32 + (((2 + hh) ^ vsw) * 8));

        o0 = __builtin_amdgcn_mfma_f32_32x32x16_bf16(A0.v, vf00, o0, 0, 0, 0);
        o0 = __builtin_amdgcn_mfma_f32_32x32x16_bf16(A1.v, vf01, o0, 0, 0, 0);
        o1 = __builtin_amdgcn_mfma_f32_32x32x16_bf16(A0.v, vf10, o1, 0, 0, 0);
        o1 = __builtin_amdgcn_mfma_f32_32x32x16_bf16(A1.v, vf11, o1, 0, 0, 0);

        cur ^= 1;
    }

#pragma unroll
    for (int r = 0; r < 16; r++) {
        int qrow = (r & 3) + 8 * (r >> 2) + 4 * hh;
        float lr = __shfl(l_run, qrow);
        float inv = 1.f / lr;
        long row = nb + q0 + qrow;
        y[row * 1024 + h * 64 + c] = f2b(o0[r] * inv);
        y[row * 1024 + h * 64 + 32 + c] = f2b(o1[r] * inv);
    }
}

// --------------------------------------------------------------------------
__global__ __launch_bounds__(256)
void zcrms_kernel(const float* __restrict__ x, const float* __restrict__ g,
                  unsigned short* __restrict__ hn)
{
    __shared__ float red[8];
    const long row = blockIdx.x;
    const int tid = threadIdx.x;
    const float* xr = x + row * 1024;
    float4 v = *(const float4*)(xr + tid * 4);
    float s = v.x + v.y + v.z + v.w;
#pragma unroll
    for (int m = 32; m; m >>= 1) s += __shfl_xor(s, m);
    const int lane = tid & 63, wid = tid >> 6;
    if (lane == 0) red[wid] = s;
    __syncthreads();
    float mean = (red[0] + red[1] + red[2] + red[3]) * (1.f / 1024.f);
    float c0 = v.x - mean, c1 = v.y - mean, c2 = v.z - mean, c3 = v.w - mean;
    float s2 = c0 * c0 + c1 * c1 + c2 * c2 + c3 * c3;
#pragma unroll
    for (int m = 32; m; m >>= 1) s2 += __shfl_xor(s2, m);
    if (lane == 0) red[4 + wid] = s2;
    __syncthreads();
    float rinv = rsqrtf((red[4] + red[5] + red[6] + red[7]) * (1.f / 1024.f) + 1e-8f);
    const float* gr = g + tid * 4;
    unsigned int lo = (unsigned int)f2b(c0 * rinv * gr[0]) | ((unsigned int)f2b(c1 * rinv * gr[1]) << 16);
    unsigned int hi = (unsigned int)f2b(c2 * rinv * gr[2]) | ((unsigned int)f2b(c3 * rinv * gr[3]) << 16);
    uint2 u; u.x = lo; u.y = hi;
    *(uint2*)(hn + row * 1024 + tid * 4) = u;
}

__global__ __launch_bounds__(1024)
void embed_kernel(const float* __restrict__ patches, const float* __restrict__ W,
                  const float* __restrict__ bias, float* __restrict__ x,
                  unsigned short* __restrict__ xpad)
{
    __shared__ float sp[8][75];
    const long r0 = (long)blockIdx.x * 8;
    const int tid = threadIdx.x;
    for (int i = tid; i < 600; i += 1024) sp[i / 75][i % 75] = patches[r0 * 75 + i];
    __syncthreads();
    float acc[8];
    float bb = bias[tid];
#pragma unroll
    for (int j = 0; j < 8; j++) acc[j] = bb;
    for (int p = 0; p < 75; p++) {
        float w = W[p * 1024 + tid];
#pragma unroll
        for (int j = 0; j < 8; j++) acc[j] += sp[j][p] * w;
    }
#pragma unroll
    for (int j = 0; j < 8; j++) {
        long r = r0 + j;
        x[r * 1024 + tid] = acc[j];
        long bb2 = r >> 10, n = r & 1023;
        xpad[(bb2 * 1028 + n + 2) * 1024 + tid] = f2b(acc[j]);
    }
}

__global__ void rope_table_kernel(float* __restrict__ tab)
{
    int idx = blockIdx.x * 256 + threadIdx.x;   // 32768
    int n = idx >> 5, i = idx & 31;
    float inv = powf(10000.0f, -(float)i * (1.0f / 32.0f));
    float ang = (float)n * inv;
    tab[idx] = cosf(ang);
    tab[32768 + idx] = sinf(ang);
}

__global__ __launch_bounds__(256)
void conv3_kernel(const unsigned short* __restrict__ h2, const float* __restrict__ w3,
                  const float* __restrict__ b3, float* __restrict__ logits)
{
    const long row = (long)blockIdx.x * 4 + (threadIdx.x >> 6);
    const int lane = threadIdx.x & 63;
    const unsigned short* hr = h2 + row * 256;
    float s = 0.f;
#pragma unroll
    for (int t = 0; t < 4; t++) s += b2f(hr[lane + t * 64]) * w3[lane + t * 64];
#pragma unroll
    for (int m = 32; m; m >>= 1) s += __shfl_xor(s, m);
    if (lane == 0) logits[row] = s + b3[0];
}

__global__ __launch_bounds__(256)
void winmax_kernel(const float* __restrict__ logits, float* __restrict__ win)
{
    __shared__ float red[4];
    const int b = blockIdx.x, tid = threadIdx.x;
    float m = -1e30f;
    for (int i = tid; i < 1024; i += 256) m = fmaxf(m, logits[b * 1024 + i]);
#pragma unroll
    for (int k = 32; k; k >>= 1) m = fmaxf(m, __shfl_xor(m, k));
    if ((tid & 63) == 0) red[tid >> 6] = m;
    __syncthreads();
    if (tid == 0) win[b] = fmaxf(fmaxf(red[0], red[1]), fmaxf(red[2], red[3]));
}

// f32 (K,Nc) -> bf16 (Nc,K), batched over z
__global__ __launch_bounds__(256)
void wtrans_kernel(const float* __restrict__ in, unsigned short* __restrict__ out,
                   int K, int Nc)
{
    __shared__ float tile[32][33];
    const long base = (long)blockIdx.z * K * Nc;
    const int k0 = blockIdx.y * 32, n0 = blockIdx.x * 32;
    const int tx = threadIdx.x & 31, ty = threadIdx.x >> 5;
#pragma unroll
    for (int r = ty; r < 32; r += 8) tile[r][tx] = in[base + (long)(k0 + r) * Nc + n0 + tx];
    __syncthreads();
#pragma unroll
    for (int r = ty; r < 32; r += 8) out[base + (long)(n0 + r) * K + k0 + tx] = f2b(tile[tx][r]);
}

// (Co,Ci,Kw) f32 -> [dk][co][ci] bf16
__global__ void wconv_tap_kernel(const float* __restrict__ in, unsigned short* __restrict__ out,
                                 int CI, int KW, int CO, long total)
{
    long idx = (long)blockIdx.x * 256 + threadIdx.x;
    if (idx >= total) return;
    int ci = (int)(idx % CI);
    long t = idx / CI;
    int co = (int)(t % CO);
    int dk = (int)(t / CO);
    out[idx] = f2b(in[((long)co * CI + ci) * KW + dk]);
}

// ---------------------------------------------------------------------------
extern "C" void kernel_launch(void* const* d_in, const int* in_sizes, int n_in,
                              void* d_out, int out_size, void* d_ws, size_t ws_size,
                              hipStream_t stream)
{
    (void)in_sizes; (void)n_in; (void)out_size; (void)ws_size;
    const float* patches = (const float*)d_in[0];
    const float* embed_w = (const float*)d_in[1];
    const float* embed_b = (const float*)d_in[2];
    const float* bd_w1 = (const float*)d_in[3];
    const float* bd_b1 = (const float*)d_in[4];
    const float* bd_w2 = (const float*)d_in[5];
    const float* bd_b2 = (const float*)d_in[6];
    const float* bd_w3 = (const float*)d_in[7];
    const float* bd_b3 = (const float*)d_in[8];
    const float* norm_g = (const float*)d_in[9];
    const float* qkv_w = (const float*)d_in[10];
    const float* qkv_b = (const float*)d_in[11];
    const float* out_w = (const float*)d_in[12];
    const float* out_b = (const float*)d_in[13];
    const float* gate_w = (const float*)d_in[14];
    const float* gate_b = (const float*)d_in[15];

    char* p = (char*)d_ws;
    auto alloc = [&](size_t bytes) { char* r = p; p += (bytes + 255) & ~(size_t)255; return r; };
    unsigned short* WQ   = (unsigned short*)alloc(3ll * 3072 * 1024 * 2);
    unsigned short* WO   = (unsigned short*)alloc(3ll * 1024 * 1024 * 2);
    unsigned short* WG   = (unsigned short*)alloc(3ll * 1024 * 1024 * 2);
    unsigned short* W1S  = (unsigned short*)alloc(5ll * 512 * 1024 * 2);
    unsigned short* W2S  = (unsigned short*)alloc(3ll * 256 * 512 * 2);
    unsigned short* XPAD = (unsigned short*)alloc(4ll * 1028 * 1024 * 2);
    unsigned short* H1P  = (unsigned short*)alloc(4ll * 1026 * 512 * 2);
    unsigned short* H2   = (unsigned short*)alloc(4ll * 1024 * 256 * 2);
    float*          X    = (float*)alloc(4ll * 1024 * 1024 * 4);
    unsigned short* HN   = (unsigned short*)alloc(4096ll * 1024 * 2);
    unsigned short* QKV  = (unsigned short*)alloc(4096ll * 3072 * 2);
    unsigned short* YATT = (unsigned short*)alloc(4096ll * 1024 * 2);
    float*          LOGI = (float*)alloc(4096 * 4);
    float*          ROPE = (float*)alloc(65536 * 4);
    // VT (B,H,64,1024) bf16 = 8MB aliased onto XPAD (conv pipeline done first)
    unsigned short* VT   = XPAD;

    hipMemsetAsync(XPAD, 0, 4ll * 1028 * 1024 * 2, stream);
    hipMemsetAsync(H1P, 0, 4ll * 1026 * 512 * 2, stream);

    wtrans_kernel<<<dim3(96, 32, 3), 256, 0, stream>>>(qkv_w, WQ, 1024, 3072);
    wtrans_kernel<<<dim3(32, 32, 3), 256, 0, stream>>>(out_w, WO, 1024, 1024);
    wtrans_kernel<<<dim3(32, 32, 3), 256, 0, stream>>>(gate_w, WG, 1024, 1024);
    wconv_tap_kernel<<<10240, 256, 0, stream>>>(bd_w1, W1S, 1024, 5, 512, 5ll * 512 * 1024);
    wconv_tap_kernel<<<1536, 256, 0, stream>>>(bd_w2, W2S, 512, 3, 256, 3ll * 256 * 512);
    rope_table_kernel<<<128, 256, 0, stream>>>(ROPE);
    embed_kernel<<<512, 1024, 0, stream>>>(patches, embed_w, embed_b, X, XPAD);

    conv_gemm<5, 1024><<<dim3(8, 8, 4), 256, 0, stream>>>(XPAD, 1028ll * 1024, W1S, 512, bd_b1,
                                                          H1P, 1026ll * 512, 512, 1);
    conv_gemm<3, 512><<<dim3(4, 8, 4), 256, 0, stream>>>(H1P, 1026ll * 512, W2S, 256, bd_b2,
                                                         H2, 1024ll * 256, 256, 0);
    conv3_kernel<<<1024, 256, 0, stream>>>(H2, bd_w3, bd_b3, LOGI);
    winmax_kernel<<<4, 256, 0, stream>>>(LOGI, (float*)d_out + 4194304);

    for (int l = 0; l < 3; l++) {
        zcrms_kernel<<<4096, 256, 0, stream>>>(X, norm_g + l * 1024, HN);
        qkv_gemm<<<dim3(24, 32), 256, 0, stream>>>(HN, WQ + (long)l * 3072 * 1024,
                                                   qkv_b + l * 3072, QKV, ROPE);
        vtrans_kernel<<<dim3(16, 64), 256, 0, stream>>>(QKV, VT);
        attn_kernel<<<dim3(64, 8), 256, 0, stream>>>(QKV, VT, LOGI, YATT);
        if (l < 2)
            fused_og<0><<<dim3(8, 32), 256, 0, stream>>>(YATT, WO + (long)l * 1024 * 1024, out_b + l * 1024,
                                                         HN, WG + (long)l * 1024 * 1024, gate_b + l * 1024,
                                                         X, nullptr);
        else
            fused_og<1><<<dim3(8, 32), 256, 0, stream>>>(YATT, WO + (long)l * 1024 * 1024, out_b + l * 1024,
                                                         HN, WG + (long)l * 1024 * 1024, gate_b + l * 1024,
                                                         X, (float*)d_out);
    }
}

// Round 5
// 532.958 us; speedup vs baseline: 1.8313x; 1.0402x over previous
//
#include <hip/hip_runtime.h>
#include <stdint.h>
#include <math.h>

typedef __attribute__((ext_vector_type(8))) short short8;
typedef __attribute__((ext_vector_type(4))) float f32x4;
typedef __attribute__((ext_vector_type(16))) float f32x16;

__device__ __forceinline__ float b2f(unsigned short u) {
    union { unsigned int i; float f; } v; v.i = ((unsigned int)u) << 16; return v.f;
}
__device__ __forceinline__ unsigned short f2b(float f) {
    union { float f; unsigned int i; } v; v.f = f;
    unsigned int r = v.i + 0x7fffu + ((v.i >> 16) & 1u);
    return (unsigned short)(r >> 16);
}
__device__ __forceinline__ unsigned int cvt_pk_bf16(float lo, float hi) {
    unsigned int r;
    asm("v_cvt_pk_bf16_f32 %0, %1, %2" : "=v"(r) : "v"(lo), "v"(hi));
    return r;
}

__device__ __forceinline__ void gload_lds16(const void* g, void* l) {
    __builtin_amdgcn_global_load_lds((__attribute__((address_space(1))) void*)g,
                                     (__attribute__((address_space(3))) void*)l,
                                     16, 0, 0);
}

// ---------------------------------------------------------------------------
// qkv GEMM with fused RoPE epilogue. Q (cols<1024) pre-scaled by
// 0.125*log2(e) so attention can use exp2 directly.
// ---------------------------------------------------------------------------
__global__ __launch_bounds__(256)
void qkv_gemm(const unsigned short* __restrict__ A,
              const unsigned short* __restrict__ Bw,
              const float* __restrict__ bias,
              unsigned short* __restrict__ Cb,
              const float* __restrict__ rope)
{
    __shared__ __align__(16) unsigned short As[128 * 32];
    __shared__ __align__(16) unsigned short Bs[128 * 32];
    const int tid = threadIdx.x;
    const int lane = tid & 63, wid = tid >> 6;
    const int wr = wid >> 1, wc = wid & 1;
    const long brow = (long)blockIdx.y * 128;
    const long bcol = (long)blockIdx.x * 128;

    const int arow = tid >> 2;
    const int acol = (tid & 3) * 8;
    const unsigned short* ga0 = A + (brow + arow) * 1024 + acol;
    const unsigned short* ga1 = A + (brow + 64 + arow) * 1024 + acol;
    const unsigned short* gb0 = Bw + (bcol + arow) * 1024 + acol;
    const unsigned short* gb1 = Bw + (bcol + 64 + arow) * 1024 + acol;
    unsigned short* la0 = As + wid * 512;
    unsigned short* la1 = As + 2048 + wid * 512;
    unsigned short* lb0 = Bs + wid * 512;
    unsigned short* lb1 = Bs + 2048 + wid * 512;

    f32x4 acc[4][4] = {};

    for (int kk = 0; kk < 1024; kk += 32) {
        gload_lds16(ga0 + kk, la0);
        gload_lds16(ga1 + kk, la1);
        gload_lds16(gb0 + kk, lb0);
        gload_lds16(gb1 + kk, lb1);
        __syncthreads();
        const int fr = lane & 15, fk = (lane >> 4) * 8;
        short8 af[4], bfrag[4];
#pragma unroll
        for (int m = 0; m < 4; m++)
            af[m] = *(const short8*)(As + (wr * 64 + m * 16 + fr) * 32 + fk);
#pragma unroll
        for (int n = 0; n < 4; n++)
            bfrag[n] = *(const short8*)(Bs + (wc * 64 + n * 16 + fr) * 32 + fk);
#pragma unroll
        for (int m = 0; m < 4; m++)
#pragma unroll
            for (int n = 0; n < 4; n++)
                acc[m][n] = __builtin_amdgcn_mfma_f32_16x16x32_bf16(af[m], bfrag[n], acc[m][n], 0, 0, 0);
        __syncthreads();
    }

    const int fr = lane & 15;
    const int fq = (lane >> 4) * 4;
#pragma unroll
    for (int m = 0; m < 4; m++) {
#pragma unroll
        for (int n = 0; n < 4; n++) {
#pragma unroll
            for (int j = 0; j < 4; j++) {
                long row = brow + wr * 64 + m * 16 + fq + j;
                int col = (int)bcol + wc * 64 + n * 16 + fr;
                float v = acc[m][n][j] + bias[col];
                float part = __shfl_xor(v, 1);   // partner col (d^1), same row
                if (col < 2048) {
                    int d = col & 63;
                    int i2 = d >> 1;
                    int ntok = (int)(row & 1023);
                    float cc = rope[ntok * 32 + i2];
                    float ss = rope[32768 + ntok * 32 + i2];
                    v = (d & 1) ? (part * ss + v * cc) : (v * cc - part * ss);
                }
                if (col < 1024) v *= 0.18033688011112042f;   // 0.125*log2(e)
                Cb[row * 3072 + col] = f2b(v);
            }
        }
    }
}

// ---------------------------------------------------------------------------
// Tap-accumulation conv-as-GEMM (unchanged).
// ---------------------------------------------------------------------------
template<int KW, int CI>
__global__ __launch_bounds__(256)
void conv_gemm(const unsigned short* __restrict__ A, long sAb,
               const unsigned short* __restrict__ Bw, int CO,
               const float* __restrict__ bias,
               unsigned short* __restrict__ C, long sCb, int ldc, int crow_off)
{
    __shared__ __align__(16) unsigned short As[2][144 * 32];
    __shared__ __align__(16) unsigned short Bs[2][KW * 64 * 32];
    const int tid = threadIdx.x, lane = tid & 63, wid = tid >> 6;
    const int wr = wid >> 1, wc = wid & 1;
    const int z = blockIdx.z;
    const long brow = (long)blockIdx.y * 128;
    const long bcol = (long)blockIdx.x * 64;
    const unsigned short* Ab = A + z * sAb + brow * CI;
    const int srow = tid >> 2, scol = (tid & 3) * 8;

    f32x4 acc[4][2] = {};

    auto STAGE = [&](int buf, int kk) {
#pragma unroll
        for (int o = 0; o < 2; o++)
            gload_lds16(Ab + (long)(o * 64 + srow) * CI + kk + scol,
                        As[buf] + (o * 64 + wid * 16) * 32);
        if (wid == 0)
            gload_lds16(Ab + (long)(128 + srow) * CI + kk + scol,
                        As[buf] + 128 * 32);
#pragma unroll
        for (int dk = 0; dk < KW; dk++)
            gload_lds16(Bw + ((long)dk * CO + bcol + srow) * CI + kk + scol,
                        Bs[buf] + (dk * 64 + wid * 16) * 32);
    };

    STAGE(0, 0);
    const int fr = lane & 15, fk = (lane >> 4) * 8;
    int cur = 0;
    for (int kk = 0; kk < CI; kk += 32) {
        __syncthreads();
        if (kk + 32 < CI) STAGE(cur ^ 1, kk + 32);
        short8 bfr[KW][2];
#pragma unroll
        for (int dk = 0; dk < KW; dk++)
#pragma unroll
            for (int n = 0; n < 2; n++)
                bfr[dk][n] = *(const short8*)(Bs[cur] + (dk * 64 + wc * 32 + n * 16 + fr) * 32 + fk);
#pragma unroll
        for (int m = 0; m < 4; m++) {
#pragma unroll
            for (int dk = 0; dk < KW; dk++) {
                short8 af = *(const short8*)(As[cur] + (wr * 64 + m * 16 + fr + dk) * 32 + fk);
#pragma unroll
                for (int n = 0; n < 2; n++)
                    acc[m][n] = __builtin_amdgcn_mfma_f32_16x16x32_bf16(af, bfr[dk][n], acc[m][n], 0, 0, 0);
            }
        }
        cur ^= 1;
    }

    const int fq = (lane >> 4) * 4;
#pragma unroll
    for (int m = 0; m < 4; m++) {
#pragma unroll
        for (int n = 0; n < 2; n++) {
#pragma unroll
            for (int j = 0; j < 4; j++) {
                long row = brow + wr * 64 + m * 16 + fq + j;
                int col = (int)bcol + wc * 32 + n * 16 + fr;
                float v = acc[m][n][j] + bias[col];
                v = v / (1.f + __expf(-v));    // silu
                C[z * sCb + (crow_off + row) * ldc + col] = f2b(v);
            }
        }
    }
}

// ---------------------------------------------------------------------------
// Fused out-proj + gate GEMMs + residual epilogue (unchanged).
// ---------------------------------------------------------------------------
template<int LAST>
__global__ __launch_bounds__(256)
void fused_og(const unsigned short* __restrict__ A1, const unsigned short* __restrict__ B1,
              const float* __restrict__ b1,
              const unsigned short* __restrict__ A2, const unsigned short* __restrict__ B2,
              const float* __restrict__ b2,
              float* __restrict__ X, float* __restrict__ OUT)
{
    __shared__ __align__(16) unsigned short S[2][4][128 * 32];
    const int tid = threadIdx.x, lane = tid & 63, wid = tid >> 6;
    const int wr = wid >> 1, wc = wid & 1;
    const long brow = (long)blockIdx.y * 128;
    const long bcol = (long)blockIdx.x * 128;
    const int srow = tid >> 2, scol = (tid & 3) * 8;

    const unsigned short* g0 = A1 + (brow + srow) * 1024 + scol;
    const unsigned short* g1 = B1 + (bcol + srow) * 1024 + scol;
    const unsigned short* g2 = A2 + (brow + srow) * 1024 + scol;
    const unsigned short* g3 = B2 + (bcol + srow) * 1024 + scol;

    f32x4 acc1[4][4] = {}, acc2[4][4] = {};

    auto STAGE = [&](int buf, int kk) {
#pragma unroll
        for (int o = 0; o < 2; o++) {
            gload_lds16(g0 + (long)o * 65536 + kk, S[buf][0] + (o * 64 + wid * 16) * 32);
            gload_lds16(g1 + (long)o * 65536 + kk, S[buf][1] + (o * 64 + wid * 16) * 32);
            gload_lds16(g2 + (long)o * 65536 + kk, S[buf][2] + (o * 64 + wid * 16) * 32);
            gload_lds16(g3 + (long)o * 65536 + kk, S[buf][3] + (o * 64 + wid * 16) * 32);
        }
    };

    STAGE(0, 0);
    const int fr = lane & 15, fk = (lane >> 4) * 8;
    int cur = 0;
    for (int kk = 0; kk < 1024; kk += 32) {
        __syncthreads();
        if (kk + 32 < 1024) STAGE(cur ^ 1, kk + 32);
        {
            short8 af[4], bf[4];
#pragma unroll
            for (int m = 0; m < 4; m++)
                af[m] = *(const short8*)(S[cur][0] + (wr * 64 + m * 16 + fr) * 32 + fk);
#pragma unroll
            for (int n = 0; n < 4; n++)
                bf[n] = *(const short8*)(S[cur][1] + (wc * 64 + n * 16 + fr) * 32 + fk);
#pragma unroll
            for (int m = 0; m < 4; m++)
#pragma unroll
                for (int n = 0; n < 4; n++)
                    acc1[m][n] = __builtin_amdgcn_mfma_f32_16x16x32_bf16(af[m], bf[n], acc1[m][n], 0, 0, 0);
        }
        {
            short8 af[4], bf[4];
#pragma unroll
            for (int m = 0; m < 4; m++)
                af[m] = *(const short8*)(S[cur][2] + (wr * 64 + m * 16 + fr) * 32 + fk);
#pragma unroll
            for (int n = 0; n < 4; n++)
                bf[n] = *(const short8*)(S[cur][3] + (wc * 64 + n * 16 + fr) * 32 + fk);
#pragma unroll
            for (int m = 0; m < 4; m++)
#pragma unroll
                for (int n = 0; n < 4; n++)
                    acc2[m][n] = __builtin_amdgcn_mfma_f32_16x16x32_bf16(af[m], bf[n], acc2[m][n], 0, 0, 0);
        }
        cur ^= 1;
    }

    const int fq = (lane >> 4) * 4;
#pragma unroll
    for (int m = 0; m < 4; m++) {
#pragma unroll
        for (int n = 0; n < 4; n++) {
#pragma unroll
            for (int j = 0; j < 4; j++) {
                long row = brow + wr * 64 + m * 16 + fq + j;
                int col = (int)bcol + wc * 64 + n * 16 + fr;
                float v1 = acc1[m][n][j] + b1[col];
                float v2 = acc2[m][n][j] + b2[col];
                long idx = row * 1024 + col;
                float r = X[idx] + v1 / (1.f + __expf(-v2));
                if (LAST) OUT[idx] = r; else X[idx] = r;
            }
        }
    }
}

// ---------------------------------------------------------------------------
// V transpose with key-order permutation:
// VTP[b][h][d][n'] = V[b][pi(n')][h][d], pi = swap bits 2,3 of n' (16-groups).
// This makes the PV A-fragment's k-positions match P's lane-local layout.
// ---------------------------------------------------------------------------
__global__ __launch_bounds__(256)
void vtrans_kernel(const unsigned short* __restrict__ qkv, unsigned short* __restrict__ vt)
{
    __shared__ unsigned short sm[64][72];
    const int nt = blockIdx.x, bh = blockIdx.y;
    const int b = bh >> 4, h = bh & 15;
    const int tid = threadIdx.x;
    const unsigned short* vsrc = qkv + ((long)b * 1024 + nt * 64) * 3072 + 2048 + h * 64;
    const int r = tid >> 2, c0 = (tid & 3) * 16;
#pragma unroll
    for (int t = 0; t < 2; t++) {
        short8 v = *(const short8*)(vsrc + (long)r * 3072 + c0 + t * 8);
        *(short8*)(&sm[r][c0 + t * 8]) = v;
    }
    __syncthreads();
    const int d = tid >> 2, n0 = (tid & 3) * 16;
    unsigned short tmp[16];
#pragma unroll
    for (int i = 0; i < 16; i++) {
        int pi = (i & 3) | ((i & 4) << 1) | ((i & 8) >> 1);   // swap bits 2,3
        tmp[i] = sm[n0 + pi][d];
    }
    unsigned short* dst = vt + ((long)bh * 64 + d) * 1024 + nt * 64 + n0;
    *(short8*)(dst) = *(const short8*)(tmp);
    *(short8*)(dst + 8) = *(const short8*)(tmp + 8);
}

// ---------------------------------------------------------------------------
// Flash attention v4: swapped-QK^T 32x32 + transposed PV (O^T = V^T·P).
// P stays lane-local (no cross-lane redistribution); softmax in exp2 domain
// (Q pre-scaled by 0.125*log2e, bias pre-scaled by log2e); P packed with
// v_cvt_pk_bf16_f32. K/V LDS-staged double-buffered w/ pre-swizzled source.
// grid (64 bh, 8 qt): XCD locality for K/V.
// ---------------------------------------------------------------------------
__global__ __launch_bounds__(256)
void attn_kernel(const unsigned short* __restrict__ qkv,
                 const unsigned short* __restrict__ vt,   // VTP (key-permuted)
                 const float* __restrict__ plog,
                 unsigned short* __restrict__ y)
{
    __shared__ __align__(16) unsigned short Kb[2][32 * 64];
    __shared__ __align__(16) unsigned short Vb[2][64 * 32];
    __shared__ float pl[1024];

    const int bh = blockIdx.x;
    const int qt = blockIdx.y;
    const int b = bh >> 4, h = bh & 15;
    const int tid = threadIdx.x, lane = tid & 63, wid = tid >> 6;
    const int c = lane & 31;
    const int hh = lane >> 5;

    const long nb = (long)b * 1024;
    const unsigned short* qbase = qkv + nb * 3072 + h * 64;
    const unsigned short* kbase = qbase + 1024;
    const unsigned short* vtb = vt + (long)bh * 65536;

    for (int i = tid; i < 1024; i += 256) pl[i] = plog[b * 1024 + i] * 1.4426950408889634f;

    // K staging: row tid>>3 (128B rows), source chunk (lane&7)^(row&7)
    const int krow = (tid >> 3) & 31;
    const int kchk = (lane & 7) ^ ((lane >> 3) & 7);
    const unsigned short* gk = kbase + (long)krow * 3072 + kchk * 8;
    unsigned short* lk = Kb[0] + wid * 512;

    // V staging: row tid>>2 (64B rows), source chunk (tid&3)^(row&3)
    const int vrow = tid >> 2;
    const int vchk = (tid & 3) ^ ((tid >> 2) & 3);
    const unsigned short* gv = vtb + (long)vrow * 1024 + vchk * 8;
    unsigned short* lv = Vb[0] + wid * 512;

    auto STAGE = [&](int buf, int kt) {
        gload_lds16(gk + (long)kt * 3072, lk + buf * 2048);
        gload_lds16(gv + kt, lv + buf * 2048);
    };

    const int q0 = qt * 128 + wid * 32;
    short8 qf[4];
#pragma unroll
    for (int d = 0; d < 4; d++)
        qf[d] = *(const short8*)(qbase + (long)(q0 + c) * 3072 + d * 16 + hh * 8);

    float m_run = -1e30f, l_run = 0.f;
    f32x16 o0 = {}, o1 = {};

    STAGE(0, 0);
    int cur = 0;
    for (int kt = 0; kt < 1024; kt += 32) {
        __syncthreads();
        if (kt + 32 < 1024) STAGE(cur ^ 1, kt + 32);

        // K fragments (row c, swizzled chunks)
        short8 kf[4];
#pragma unroll
        for (int d = 0; d < 4; d++)
            kf[d] = *(const short8*)(Kb[cur] + c * 64 + (((2 * d + hh) ^ (c & 7)) * 8));

        f32x16 s = {};
#pragma unroll
        for (int d = 0; d < 4; d++)
            s = __builtin_amdgcn_mfma_f32_32x32x16_bf16(kf[d], qf[d], s, 0, 0, 0);

        // bias + per-lane max over own 16 keys of q=c (scores in log2 domain)
        float mx = -1e30f;
#pragma unroll
        for (int r = 0; r < 16; r++) {
            int key = (r & 3) + 8 * (r >> 2) + 4 * hh;
            float pv = s[r] + pl[kt + key];
            s[r] = pv;
            mx = fmaxf(mx, pv);
        }
        mx = fmaxf(mx, __shfl_xor(mx, 32));

        if (!__all(mx - m_run <= 11.5f)) {     // defer-max (T13, log2 domain)
            float mnew = fmaxf(m_run, mx);
            float f = __builtin_amdgcn_exp2f(m_run - mnew);
            l_run *= f;
#pragma unroll
            for (int r = 0; r < 16; r++) { o0[r] *= f; o1[r] *= f; }
            m_run = mnew;
        }

        float sum = 0.f;
#pragma unroll
        for (int r = 0; r < 16; r++) {
            s[r] = __builtin_amdgcn_exp2f(s[r] - m_run);
            sum += s[r];
        }
        sum += __shfl_xor(sum, 32);
        l_run += sum;

        // pack P into PV B-fragments (lane-local; k-positions = hh*8+j)
        union U8 { unsigned int u[4]; short8 v; } B1, B2;
#pragma unroll
        for (int t = 0; t < 4; t++) {
            B1.u[t] = cvt_pk_bf16(s[2 * t], s[2 * t + 1]);
            B2.u[t] = cvt_pk_bf16(s[8 + 2 * t], s[9 + 2 * t]);
        }

        // V^T A-fragments: rows c / c+32, logical chunk (kh*2+hh)^(c&3)
        short8 va00 = *(const short8*)(Vb[cur] + c * 32 + ((hh ^ (c & 3)) * 8));
        short8 va01 = *(const short8*)(Vb[cur] + c * 32 + (((2 + hh) ^ (c & 3)) * 8));
        short8 va10 = *(const short8*)(Vb[cur] + (c + 32) * 32 + ((hh ^ (c & 3)) * 8));
        short8 va11 = *(const short8*)(Vb[cur] + (c + 32) * 32 + (((2 + hh) ^ (c & 3)) * 8));

        // O^T[d][q] += V^T[d][k] P[k][q]
        o0 = __builtin_amdgcn_mfma_f32_32x32x16_bf16(va00, B1.v, o0, 0, 0, 0);
        o0 = __builtin_amdgcn_mfma_f32_32x32x16_bf16(va01, B2.v, o0, 0, 0, 0);
        o1 = __builtin_amdgcn_mfma_f32_32x32x16_bf16(va10, B1.v, o1, 0, 0, 0);
        o1 = __builtin_amdgcn_mfma_f32_32x32x16_bf16(va11, B2.v, o1, 0, 0, 0);

        cur ^= 1;
    }

    // epilogue: q = c is lane-local; o regs hold d = (r&3)+8*(r>>2)+4*hh
    float inv = 1.f / l_run;
    unsigned short* yr = y + (nb + q0 + c) * 1024 + h * 64;
#pragma unroll
    for (int a = 0; a < 4; a++) {
        int d0 = 8 * a + 4 * hh;
        *(unsigned int*)(yr + d0)      = cvt_pk_bf16(o0[4 * a] * inv, o0[4 * a + 1] * inv);
        *(unsigned int*)(yr + d0 + 2)  = cvt_pk_bf16(o0[4 * a + 2] * inv, o0[4 * a + 3] * inv);
        *(unsigned int*)(yr + 32 + d0)     = cvt_pk_bf16(o1[4 * a] * inv, o1[4 * a + 1] * inv);
        *(unsigned int*)(yr + 32 + d0 + 2) = cvt_pk_bf16(o1[4 * a + 2] * inv, o1[4 * a + 3] * inv);
    }
}

// --------------------------------------------------------------------------
__global__ __launch_bounds__(256)
void zcrms_kernel(const float* __restrict__ x, const float* __restrict__ g,
                  unsigned short* __restrict__ hn)
{
    __shared__ float red[8];
    const long row = blockIdx.x;
    const int tid = threadIdx.x;
    const float* xr = x + row * 1024;
    float4 v = *(const float4*)(xr + tid * 4);
    float s = v.x + v.y + v.z + v.w;
#pragma unroll
    for (int m = 32; m; m >>= 1) s += __shfl_xor(s, m);
    const int lane = tid & 63, wid = tid >> 6;
    if (lane == 0) red[wid] = s;
    __syncthreads();
    float mean = (red[0] + red[1] + red[2] + red[3]) * (1.f / 1024.f);
    float c0 = v.x - mean, c1 = v.y - mean, c2 = v.z - mean, c3 = v.w - mean;
    float s2 = c0 * c0 + c1 * c1 + c2 * c2 + c3 * c3;
#pragma unroll
    for (int m = 32; m; m >>= 1) s2 += __shfl_xor(s2, m);
    if (lane == 0) red[4 + wid] = s2;
    __syncthreads();
    float rinv = rsqrtf((red[4] + red[5] + red[6] + red[7]) * (1.f / 1024.f) + 1e-8f);
    const float* gr = g + tid * 4;
    unsigned int lo = (unsigned int)f2b(c0 * rinv * gr[0]) | ((unsigned int)f2b(c1 * rinv * gr[1]) << 16);
    unsigned int hi = (unsigned int)f2b(c2 * rinv * gr[2]) | ((unsigned int)f2b(c3 * rinv * gr[3]) << 16);
    uint2 u; u.x = lo; u.y = hi;
    *(uint2*)(hn + row * 1024 + tid * 4) = u;
}

__global__ __launch_bounds__(1024)
void embed_kernel(const float* __restrict__ patches, const float* __restrict__ W,
                  const float* __restrict__ bias, float* __restrict__ x,
                  unsigned short* __restrict__ xpad)
{
    __shared__ float sp[8][75];
    const long r0 = (long)blockIdx.x * 8;
    const int tid = threadIdx.x;
    for (int i = tid; i < 600; i += 1024) sp[i / 75][i % 75] = patches[r0 * 75 + i];
    __syncthreads();
    float acc[8];
    float bb = bias[tid];
#pragma unroll
    for (int j = 0; j < 8; j++) acc[j] = bb;
    for (int p = 0; p < 75; p++) {
        float w = W[p * 1024 + tid];
#pragma unroll
        for (int j = 0; j < 8; j++) acc[j] += sp[j][p] * w;
    }
#pragma unroll
    for (int j = 0; j < 8; j++) {
        long r = r0 + j;
        x[r * 1024 + tid] = acc[j];
        long bb2 = r >> 10, n = r & 1023;
        xpad[(bb2 * 1028 + n + 2) * 1024 + tid] = f2b(acc[j]);
    }
}

__global__ void rope_table_kernel(float* __restrict__ tab)
{
    int idx = blockIdx.x * 256 + threadIdx.x;   // 32768
    int n = idx >> 5, i = idx & 31;
    float inv = powf(10000.0f, -(float)i * (1.0f / 32.0f));
    float ang = (float)n * inv;
    tab[idx] = cosf(ang);
    tab[32768 + idx] = sinf(ang);
}

__global__ __launch_bounds__(256)
void conv3_kernel(const unsigned short* __restrict__ h2, const float* __restrict__ w3,
                  const float* __restrict__ b3, float* __restrict__ logits)
{
    const long row = (long)blockIdx.x * 4 + (threadIdx.x >> 6);
    const int lane = threadIdx.x & 63;
    const unsigned short* hr = h2 + row * 256;
    float s = 0.f;
#pragma unroll
    for (int t = 0; t < 4; t++) s += b2f(hr[lane + t * 64]) * w3[lane + t * 64];
#pragma unroll
    for (int m = 32; m; m >>= 1) s += __shfl_xor(s, m);
    if (lane == 0) logits[row] = s + b3[0];
}

__global__ __launch_bounds__(256)
void winmax_kernel(const float* __restrict__ logits, float* __restrict__ win)
{
    __shared__ float red[4];
    const int b = blockIdx.x, tid = threadIdx.x;
    float m = -1e30f;
    for (int i = tid; i < 1024; i += 256) m = fmaxf(m, logits[b * 1024 + i]);
#pragma unroll
    for (int k = 32; k; k >>= 1) m = fmaxf(m, __shfl_xor(m, k));
    if ((tid & 63) == 0) red[tid >> 6] = m;
    __syncthreads();
    if (tid == 0) win[b] = fmaxf(fmaxf(red[0], red[1]), fmaxf(red[2], red[3]));
}

// f32 (K,Nc) -> bf16 (Nc,K), batched over z
__global__ __launch_bounds__(256)
void wtrans_kernel(const float* __restrict__ in, unsigned short* __restrict__ out,
                   int K, int Nc)
{
    __shared__ float tile[32][33];
    const long base = (long)blockIdx.z * K * Nc;
    const int k0 = blockIdx.y * 32, n0 = blockIdx.x * 32;
    const int tx = threadIdx.x & 31, ty = threadIdx.x >> 5;
#pragma unroll
    for (int r = ty; r < 32; r += 8) tile[r][tx] = in[base + (long)(k0 + r) * Nc + n0 + tx];
    __syncthreads();
#pragma unroll
    for (int r = ty; r < 32; r += 8) out[base + (long)(n0 + r) * K + k0 + tx] = f2b(tile[tx][r]);
}

// (Co,Ci,Kw) f32 -> [dk][co][ci] bf16
__global__ void wconv_tap_kernel(const float* __restrict__ in, unsigned short* __restrict__ out,
                                 int CI, int KW, int CO, long total)
{
    long idx = (long)blockIdx.x * 256 + threadIdx.x;
    if (idx >= total) return;
    int ci = (int)(idx % CI);
    long t = idx / CI;
    int co = (int)(t % CO);
    int dk = (int)(t / CO);
    out[idx] = f2b(in[((long)co * CI + ci) * KW + dk]);
}

// ---------------------------------------------------------------------------
extern "C" void kernel_launch(void* const* d_in, const int* in_sizes, int n_in,
                              void* d_out, int out_size, void* d_ws, size_t ws_size,
                              hipStream_t stream)
{
    (void)in_sizes; (void)n_in; (void)out_size; (void)ws_size;
    const float* patches = (const float*)d_in[0];
    const float* embed_w = (const float*)d_in[1];
    const float* embed_b = (const float*)d_in[2];
    const float* bd_w1 = (const float*)d_in[3];
    const float* bd_b1 = (const float*)d_in[4];
    const float* bd_w2 = (const float*)d_in[5];
    const float* bd_b2 = (const float*)d_in[6];
    const float* bd_w3 = (const float*)d_in[7];
    const float* bd_b3 = (const float*)d_in[8];
    const float* norm_g = (const float*)d_in[9];
    const float* qkv_w = (const float*)d_in[10];
    const float* qkv_b = (const float*)d_in[11];
    const float* out_w = (const float*)d_in[12];
    const float* out_b = (const float*)d_in[13];
    const float* gate_w = (const float*)d_in[14];
    const float* gate_b = (const float*)d_in[15];

    char* p = (char*)d_ws;
    auto alloc = [&](size_t bytes) { char* r = p; p += (bytes + 255) & ~(size_t)255; return r; };
    unsigned short* WQ   = (unsigned short*)alloc(3ll * 3072 * 1024 * 2);
    unsigned short* WO   = (unsigned short*)alloc(3ll * 1024 * 1024 * 2);
    unsigned short* WG   = (unsigned short*)alloc(3ll * 1024 * 1024 * 2);
    unsigned short* W1S  = (unsigned short*)alloc(5ll * 512 * 1024 * 2);
    unsigned short* W2S  = (unsigned short*)alloc(3ll * 256 * 512 * 2);
    unsigned short* XPAD = (unsigned short*)alloc(4ll * 1028 * 1024 * 2);
    unsigned short* H1P  = (unsigned short*)alloc(4ll * 1026 * 512 * 2);
    unsigned short* H2   = (unsigned short*)alloc(4ll * 1024 * 256 * 2);
    float*          X    = (float*)alloc(4ll * 1024 * 1024 * 4);
    unsigned short* HN   = (unsigned short*)alloc(4096ll * 1024 * 2);
    unsigned short* QKV  = (unsigned short*)alloc(4096ll * 3072 * 2);
    unsigned short* YATT = (unsigned short*)alloc(4096ll * 1024 * 2);
    float*          LOGI = (float*)alloc(4096 * 4);
    float*          ROPE = (float*)alloc(65536 * 4);
    // VTP (B,H,64,1024) bf16 = 8MB aliased onto XPAD (conv pipeline done first)
    unsigned short* VT   = XPAD;

    hipMemsetAsync(XPAD, 0, 4ll * 1028 * 1024 * 2, stream);
    hipMemsetAsync(H1P, 0, 4ll * 1026 * 512 * 2, stream);

    wtrans_kernel<<<dim3(96, 32, 3), 256, 0, stream>>>(qkv_w, WQ, 1024, 3072);
    wtrans_kernel<<<dim3(32, 32, 3), 256, 0, stream>>>(out_w, WO, 1024, 1024);
    wtrans_kernel<<<dim3(32, 32, 3), 256, 0, stream>>>(gate_w, WG, 1024, 1024);
    wconv_tap_kernel<<<10240, 256, 0, stream>>>(bd_w1, W1S, 1024, 5, 512, 5ll * 512 * 1024);
    wconv_tap_kernel<<<1536, 256, 0, stream>>>(bd_w2, W2S, 512, 3, 256, 3ll * 256 * 512);
    rope_table_kernel<<<128, 256, 0, stream>>>(ROPE);
    embed_kernel<<<512, 1024, 0, stream>>>(patches, embed_w, embed_b, X, XPAD);

    conv_gemm<5, 1024><<<dim3(8, 8, 4), 256, 0, stream>>>(XPAD, 1028ll * 1024, W1S, 512, bd_b1,
                                                          H1P, 1026ll * 512, 512, 1);
    conv_gemm<3, 512><<<dim3(4, 8, 4), 256, 0, stream>>>(H1P, 1026ll * 512, W2S, 256, bd_b2,
                                                         H2, 1024ll * 256, 256, 0);
    conv3_kernel<<<1024, 256, 0, stream>>>(H2, bd_w3, bd_b3, LOGI);
    winmax_kernel<<<4, 256, 0, stream>>>(LOGI, (float*)d_out + 4194304);

    for (int l = 0; l < 3; l++) {
        zcrms_kernel<<<4096, 256, 0, stream>>>(X, norm_g + l * 1024, HN);
        qkv_gemm<<<dim3(24, 32), 256, 0, stream>>>(HN, WQ + (long)l * 3072 * 1024,
                                                   qkv_b + l * 3072, QKV, ROPE);
        vtrans_kernel<<<dim3(16, 64), 256, 0, stream>>>(QKV, VT);
        attn_kernel<<<dim3(64, 8), 256, 0, stream>>>(QKV, VT, LOGI, YATT);
        if (l < 2)
            fused_og<0><<<dim3(8, 32), 256, 0, stream>>>(YATT, WO + (long)l * 1024 * 1024, out_b + l * 1024,
                                                         HN, WG + (long)l * 1024 * 1024, gate_b + l * 1024,
                                                         X, nullptr);
        else
            fused_og<1><<<dim3(8, 32), 256, 0, stream>>>(YATT, WO + (long)l * 1024 * 1024, out_b + l * 1024,
                                                         HN, WG + (long)l * 1024 * 1024, gate_b + l * 1024,
                                                         X, (float*)d_out);
    }
}